// Round 10
// baseline (416.527 us; speedup 1.0000x reference)
//
#include <hip/hip_runtime.h>
#include <cstdint>

#define DM   1024
#define NH   16
#define DK   64
#define DFF  2688
#define SEQ  2048
#define BB   2
#define MTOT (BB*SEQ)   // 4096

typedef __attribute__((ext_vector_type(8))) short short8;
typedef __attribute__((ext_vector_type(4))) float f32x4;

typedef const __attribute__((address_space(1))) void* gaddr_t;
typedef __attribute__((address_space(3))) void* laddr_t;
#define GLOAD_LDS16(g, l) __builtin_amdgcn_global_load_lds((gaddr_t)(g), (laddr_t)(l), 16, 0, 0)
#define MFMA16(a, b, c) __builtin_amdgcn_mfma_f32_16x16x32_bf16((a), (b), (c), 0, 0, 0)
#define WAIT_LDS() __builtin_amdgcn_s_waitcnt(0xc07f)   // lgkmcnt(0) only

// counted-vmcnt sync primitives (r6/r8-proven correct).  Raw s_barrier does
// NOT drain vmcnt (unlike __syncthreads) -- loads stay in flight across it.
#define VMCNT(n) asm volatile("s_waitcnt vmcnt(" #n ")" ::: "memory")
#define BAR() do { asm volatile("" ::: "memory"); \
                   __builtin_amdgcn_s_barrier();  \
                   asm volatile("" ::: "memory"); } while (0)

__device__ __forceinline__ float bf2f(unsigned short u) {
    union { unsigned int i; float f; } v; v.i = ((unsigned int)u) << 16; return v.f;
}
__device__ __forceinline__ unsigned short f2bf(float f) {
    union { float f; unsigned int i; } v; v.f = f;
    unsigned int r = v.i + 0x7fffu + ((v.i >> 16) & 1u);
    return (unsigned short)(r >> 16);
}
__device__ __forceinline__ unsigned long long pack4bf(float a, float b, float c, float d) {
    return (unsigned long long)f2bf(a) | ((unsigned long long)f2bf(b) << 16)
         | ((unsigned long long)f2bf(c) << 32) | ((unsigned long long)f2bf(d) << 48);
}

// XCD-banded block bijection for gemm_thin (requires gridDim.y == 32).
__device__ __forceinline__ void band_swizzle(int& bx, int& by) {
    const int gx = gridDim.x;
    const int lin = blockIdx.y * gx + blockIdx.x;
    const int xcd = lin & 7, k = lin >> 3;
    by = xcd * 4 + (k & 3);
    bx = k >> 2;
}

// ---------------- fused fp32->bf16 weight convert (all 7 weights, 1 launch) ----
__global__ __launch_bounds__(256)
void prep_k(const float* __restrict__ q_w, const float* __restrict__ k_w,
            const float* __restrict__ v_w, const float* __restrict__ o_w,
            const float* __restrict__ w1_w, const float* __restrict__ w3_w,
            const float* __restrict__ w2_w,
            unsigned short* __restrict__ Wqkv, unsigned short* __restrict__ Wo,
            unsigned short* __restrict__ W13, unsigned short* __restrict__ W2) {
    const int blk = blockIdx.x;
    const float* src; unsigned short* dst; int cols, rmul, roff, i;
    if (blk < 4096) {
        const int rr = blk >> 10;
        i = (blk & 1023) * 256 + threadIdx.x;
        cols = 1024; rmul = 1;
        if (rr == 0)      { src = q_w; dst = Wqkv; roff = 0; }
        else if (rr == 1) { src = k_w; dst = Wqkv; roff = 1024; }
        else if (rr == 2) { src = v_w; dst = Wqkv; roff = 2048; }
        else              { src = o_w; dst = Wo;   roff = 0; }
    } else if (blk < 6784) {
        i = (blk - 4096) * 256 + threadIdx.x; src = w1_w; dst = W13; cols = 1024; rmul = 2; roff = 0;
    } else if (blk < 9472) {
        i = (blk - 6784) * 256 + threadIdx.x; src = w3_w; dst = W13; cols = 1024; rmul = 2; roff = 1;
    } else {
        i = (blk - 9472) * 256 + threadIdx.x; src = w2_w; dst = W2;  cols = 2688; rmul = 1; roff = 0;
    }
    const int e = i * 4;
    const int r = e / cols, c = e - r * cols;
    const float4 v = *(const float4*)(src + e);
    ushort4 o;
    o.x = f2bf(v.x); o.y = f2bf(v.y); o.z = f2bf(v.z); o.w = f2bf(v.w);
    *(ushort4*)(dst + (size_t)(r * rmul + roff) * cols + c) = o;
}

// ---------------- RMSNorm (row of 1024), fp32 in -> bf16 out -------------------
__global__ __launch_bounds__(256)
void rmsnorm_k(const float* __restrict__ x, const float* __restrict__ w,
               unsigned short* __restrict__ out) {
    const int row = blockIdx.x;
    const int tid = threadIdx.x;
    const float4 v = ((const float4*)(x + (size_t)row * DM))[tid];
    float ss = v.x * v.x + v.y * v.y + v.z * v.z + v.w * v.w;
#pragma unroll
    for (int off = 32; off > 0; off >>= 1) ss += __shfl_down(ss, off, 64);
    __shared__ float sred[4];
    const int wave = tid >> 6, lane = tid & 63;
    if (lane == 0) sred[wave] = ss;
    __syncthreads();
    const float tot = sred[0] + sred[1] + sred[2] + sred[3];
    const float rinv = rsqrtf(tot * (1.0f / DM) + 1e-5f);
    const float4 wv = ((const float4*)w)[tid];
    ushort4 o;
    o.x = f2bf(v.x * wv.x * rinv);
    o.y = f2bf(v.y * wv.y * rinv);
    o.z = f2bf(v.z * wv.z * rinv);
    o.w = f2bf(v.w * wv.w * rinv);
    ((ushort4*)(out + (size_t)row * DM))[tid] = o;
}

// ---------------- rope table ---------------------------------------------------
__global__ void rope_tab_k(const int* __restrict__ pos, float* __restrict__ tab) {
    const int s = blockIdx.x, t = threadIdx.x;
    const int kk = t & 31;
    const float ang = (float)pos[s] * __expf(-0.28782313662f * (float)kk); // 10000^(-kk/32)
    tab[s * 64 + t] = (t < 32) ? cosf(ang) : sinf(ang);
}

// ======== 128x192 GEMM: BK=64, 8 waves, 2-phase interleave, 2 BLOCKS/CU (r10) ==
// r10 tests the one untested cell: r8's fine phase-interleave + counted vmcnt
// AT 2 RESIDENT BLOCKS/CU.  LDS = 80 KB exactly (A 2x16KB + B 2x24KB) -> two
// blocks fill the 160 KB pool; __launch_bounds__(512,4) holds VGPR <= 128 so
// 4 waves/SIMD co-schedule.  Two independent barrier groups per CU: one
// block's rendezvous/vmcnt stall runs under the other block's MFMA phases.
// Ledger: 5 loads/thread/K-tile (A2+B3).  Entering iter t: 5 outstanding
// (tile t).  Preamble issues A(t+1) (2) -> 7 -> VMCNT(2) proves tile t's 5
// landed, keeps A(t+1) flying -> BAR rendezvous.  Phase 0 issues B(t+1) (3)
// -> 5 outstanding at next preamble.  Phase BAR x2; last doubles as WAR fence.
// Per phase: 4 ds_read (af m-pair) + 12 MFMA (2m x 3n x 2kk) with setprio.
// Summation order per element unchanged -> bit-identical output.
// Grids: QKV 16x32=512 = exactly one co-resident round; FFN 28x32=896 (%8==0).
// Transposed acc: lane holds row r=m0+wr+m*16+l15, cols cc..cc+3 (consecutive)
// EPI 0: fused RoPE epilogue -> QR/KR/VT   EPI 1: fused SiLU -> ACT (N/2 cols)
template <int EPI>
__global__ __launch_bounds__(512, 4)
void gemm192(const unsigned short* __restrict__ A,
             const unsigned short* __restrict__ B,
             unsigned short* __restrict__ O0,   // EPI0: QR   EPI1: ACT
             unsigned short* __restrict__ O1,   // EPI0: KR
             unsigned short* __restrict__ O2,   // EPI0: VT
             const float* __restrict__ ROPT,
             int N, int K) {
    __shared__ unsigned short As[2][8192];   // [8 koct][128 row][8 shorts] = 16 KB each
    __shared__ unsigned short Bs[2][12288];  // [8 koct][192 row][8 shorts] = 24 KB each
    const int tid = threadIdx.x;
    const int wave = tid >> 6, lane = tid & 63;
    const int l15 = lane & 15, quad = lane >> 4;

    // bijective XCD-chunked swizzle (nwg % 8 == 0: 512 / 896)
    const int gx = gridDim.x;
    const int nwg = gx * gridDim.y;
    const int lin = blockIdx.y * gx + blockIdx.x;
    const int swz = (lin & 7) * (nwg >> 3) + (lin >> 3);
    const int bx = swz % gx, by = swz / gx;
    const int m0 = by * 128, n0 = bx * 192;
    const int wr = (wave >> 2) * 64, wc = (wave & 3) * 48;

    const f32x4 z4 = {0.f, 0.f, 0.f, 0.f};
    f32x4 acc[4][3];
#pragma unroll
    for (int m = 0; m < 4; m++)
#pragma unroll
        for (int n = 0; n < 3; n++) acc[m][n] = z4;

    // staging: A = 1024 slots (2/thread, koct=s>>7,row=s&127);
    //          B = 1536 slots (3/thread, koct=s/192,row=s%192); 16 B/slot
    const unsigned short* pa[2];
    int la[2];
#pragma unroll
    for (int r = 0; r < 2; r++) {
        const int s = r * 512 + tid;
        pa[r] = A + (size_t)(m0 + (s & 127)) * K + (s >> 7) * 8;
        la[r] = (r * 512 + wave * 64) * 8;    // wave-uniform base; +lane*16B by HW
    }
    const unsigned short* pb[3];
    int lb[3];
#pragma unroll
    for (int r = 0; r < 3; r++) {
        const int s = r * 512 + tid;
        const int bk = s / 192, br = s - bk * 192;
        pb[r] = B + (size_t)(n0 + br) * K + bk * 8;
        lb[r] = (r * 512 + wave * 64) * 8;
    }

    const int nt = K >> 6;   // 16 K-tiles at K=1024

    // prologue: issue tile 0 stages (no drain -- iter 0's vmcnt handles it)
#pragma unroll
    for (int r = 0; r < 2; r++) { GLOAD_LDS16(pa[r], &As[0][la[r]]); pa[r] += 64; }
#pragma unroll
    for (int r = 0; r < 3; r++) { GLOAD_LDS16(pb[r], &Bs[0][lb[r]]); pb[r] += 64; }

    int cur = 0;
    for (int t = 0; t < nt; ++t) {
        const int nb = cur ^ 1;
        // ---- preamble: stage A(t+1), counted wait, rendezvous ----
        if (t + 1 < nt) {
#pragma unroll
            for (int r = 0; r < 2; r++) { GLOAD_LDS16(pa[r], &As[nb][la[r]]); pa[r] += 64; }
            VMCNT(2);      // tile t's 5 landed; A(t+1)'s 2 stay in flight
        } else {
            VMCNT(0);      // tail: drain
        }
        BAR();             // rendezvous: everyone's tile-t stores visible

        short8 bg[3][2];   // B fragments: read once per K-tile, live both phases
#pragma unroll
        for (int n = 0; n < 3; n++)
#pragma unroll
            for (int kk = 0; kk < 2; kk++)
                bg[n][kk] = *(const short8*)(&Bs[cur][((quad + 4 * kk) * 192 + wc + n * 16 + l15) * 8]);

#pragma unroll
        for (int p = 0; p < 2; ++p) {
            if (p == 0 && t + 1 < nt) {      // stage B(t+1) under phase-0 compute
#pragma unroll
                for (int r = 0; r < 3; r++) { GLOAD_LDS16(pb[r], &Bs[nb][lb[r]]); pb[r] += 64; }
            }
            short8 af[2][2];
#pragma unroll
            for (int m = 0; m < 2; m++)
#pragma unroll
                for (int kk = 0; kk < 2; kk++)
                    af[m][kk] = *(const short8*)(&As[cur][((quad + 4 * kk) * 128 + wr + (p * 2 + m) * 16 + l15) * 8]);
            __builtin_amdgcn_s_setprio(1);
#pragma unroll
            for (int m = 0; m < 2; m++)
#pragma unroll
                for (int n = 0; n < 3; n++)
#pragma unroll
                    for (int kk = 0; kk < 2; kk++)
                        acc[p * 2 + m][n] = MFMA16(bg[n][kk], af[m][kk], acc[p * 2 + m][n]);
            __builtin_amdgcn_s_setprio(0);
            BAR();         // phase-lock; final one doubles as iter-end WAR fence
        }
        cur = nb;
    }

#pragma unroll
    for (int m = 0; m < 4; m++) {
        const int r = m0 + wr + m * 16 + l15;     // token row
        if (EPI == 0) {
            const int b = r >> 11, s = r & (SEQ - 1);
            const float* rt = ROPT + s * 64;
#pragma unroll
            for (int n = 0; n < 3; n++) {
                const int cb = n0 + wc + n * 16;          // uniform per n (16-granular)
                const int sec = cb >> 10;                  // 0=Q 1=K 2=V
                const int h = (cb & 1023) >> 6;
                const int cc0 = (cb & 63) + quad * 4;      // even
                const f32x4 a = acc[m][n];
                if (sec < 2) {
                    const int p0 = cc0 >> 1;
                    const float cA = rt[p0],     sA = rt[32 + p0];
                    const float cB = rt[p0 + 1], sB = rt[32 + p0 + 1];
                    const float e0 = a[0] * cA - a[1] * sA;
                    const float o0 = a[0] * sA + a[1] * cA;
                    const float e1 = a[2] * cB - a[3] * sB;
                    const float o1 = a[2] * sB + a[3] * cB;
                    unsigned short* dst = (sec == 0) ? O0 : O1;
                    *(unsigned long long*)(dst + ((size_t)(b * NH + h) * SEQ + s) * DK + cc0) =
                        pack4bf(e0, o0, e1, o1);
                } else {
                    unsigned short* dst = O2 + ((size_t)(b * NH + h) * DK) * SEQ + s;
#pragma unroll
                    for (int tq = 0; tq < 4; tq++)
                        dst[(size_t)(cc0 + tq) * SEQ] = f2bf(a[tq]);
                }
            }
        } else {
#pragma unroll
            for (int n = 0; n < 3; n++) {
                const int cc = n0 + wc + n * 16 + quad * 4;   // even
                const f32x4 a = acc[m][n];
                const float s1 = a[0] * a[1] / (1.f + __expf(-a[0]));
                const float s2 = a[2] * a[3] / (1.f + __expf(-a[2]));
                *(unsigned int*)(O0 + (size_t)r * (DFF) + (cc >> 1)) =
                    (unsigned int)f2bf(s1) | ((unsigned int)f2bf(s2) << 16);
            }
        }
    }
}

// ---------------- thin-N GEMM: 128x64 block, BK=64, 4 blocks/CU ----------------
// r7 version: XCD-banded swizzle (A-panel pinning).  EPI: fp32 out = acc + R.
__global__ __launch_bounds__(256, 4)
void gemm_thin(const unsigned short* __restrict__ A,
               const unsigned short* __restrict__ B,
               float* __restrict__ Cf,
               const float* __restrict__ R,
               int N, int K) {
    __shared__ unsigned short As[8192];
    __shared__ unsigned short Bs[4096];
    const int tid = threadIdx.x;
    const int wave = tid >> 6, lane = tid & 63;
    const int l15 = lane & 15, quad = lane >> 4;
    int bx, by;
    band_swizzle(bx, by);
    const int m0 = by * 128, n0 = bx * 64;
    const int wr = (wave & 1) * 64, wc = (wave >> 1) * 32;

    const f32x4 z4 = {0.f, 0.f, 0.f, 0.f};
    f32x4 acc[4][2];
#pragma unroll
    for (int i = 0; i < 4; i++)
#pragma unroll
        for (int j = 0; j < 2; j++) acc[i][j] = z4;

    const unsigned short* ap[4];
    int al[4];
#pragma unroll
    for (int i = 0; i < 4; i++) {
        const int s = i * 256 + tid;
        ap[i] = A + (size_t)(m0 + (s & 127)) * K + (s >> 7) * 8;
        al[i] = (i * 256 + wave * 64) * 8;
    }
    const unsigned short* bp[2];
    int bl[2];
#pragma unroll
    for (int i = 0; i < 2; i++) {
        const int s = i * 256 + tid;
        bp[i] = B + (size_t)(n0 + (s & 63)) * K + (s >> 6) * 8;
        bl[i] = (i * 256 + wave * 64) * 8;
    }

    const int nk = K >> 6;
    for (int kc = 0; kc < nk; kc++) {
        __syncthreads();
#pragma unroll
        for (int i = 0; i < 4; i++) { GLOAD_LDS16(ap[i], &As[al[i]]); ap[i] += 64; }
#pragma unroll
        for (int i = 0; i < 2; i++) { GLOAD_LDS16(bp[i], &Bs[bl[i]]); bp[i] += 64; }
        __syncthreads();
#pragma unroll
        for (int h = 0; h < 2; h++) {
            short8 af[4], bg[2];
#pragma unroll
            for (int t = 0; t < 4; t++)
                af[t] = *(const short8*)(&As[((quad + 4 * h) * 128 + wr + t * 16 + l15) * 8]);
#pragma unroll
            for (int t = 0; t < 2; t++)
                bg[t] = *(const short8*)(&Bs[((quad + 4 * h) * 64 + wc + t * 16 + l15) * 8]);
#pragma unroll
            for (int i = 0; i < 4; i++)
#pragma unroll
                for (int j = 0; j < 2; j++)
                    acc[i][j] = MFMA16(bg[j], af[i], acc[i][j]);
        }
    }

#pragma unroll
    for (int i = 0; i < 4; i++) {
        const int r = m0 + wr + i * 16 + l15;
#pragma unroll
        for (int j = 0; j < 2; j++) {
            const int cc = n0 + wc + j * 16 + quad * 4;
            const size_t idx = (size_t)r * N + cc;
            const float4 rv = *(const float4*)(R + idx);
            float4 ov;
            ov.x = acc[i][j][0] + rv.x;
            ov.y = acc[i][j][1] + rv.y;
            ov.z = acc[i][j][2] + rv.z;
            ov.w = acc[i][j][3] + rv.w;
            *(float4*)(Cf + idx) = ov;
        }
    }
}

// ---------------- softmax tile update (max-free, per-lane partial li) ----------
template <bool MASK>
__device__ __forceinline__ void softmax_tile(f32x4 st[4], float& li, unsigned short* Pw,
                                             int l15, int quad, int j0, int myq) {
    float lsum = 0.f;
#pragma unroll
    for (int t = 0; t < 4; t++) {
#pragma unroll
        for (int r = 0; r < 4; r++) {
            float v = st[t][r] * 0.125f;
            if (MASK) {
                const int key = j0 + t * 16 + quad * 4 + r;
                if (key > myq) v = -1e30f;
            }
            const float p = __expf(v);
            st[t][r] = p;
            lsum += p;
        }
        *(unsigned long long*)(Pw + l15 * 72 + t * 16 + quad * 4) =
            pack4bf(st[t][0], st[t][1], st[t][2], st[t][3]);
    }
    li += lsum;
}

// ---------------- Flash attention v3: block-staged K/V, paired q-tiles ---------
__global__ __launch_bounds__(256, 2)
void attn_k(const unsigned short* __restrict__ Qr, const unsigned short* __restrict__ Kr,
            const unsigned short* __restrict__ Vt, unsigned short* __restrict__ ctx) {
    __shared__ unsigned short KVl[2][8192];
    __shared__ unsigned short Pl[4 * 2 * 1152];
    const int tid = threadIdx.x;
    const int wave = tid >> 6, lane = tid & 63;
    const int l15 = lane & 15, quad = lane >> 4;
    const int bh = blockIdx.y, b = bh >> 4, h = bh & 15;
    const int g = blockIdx.x;
    const int qtA = g * 4 + wave, qtB = 127 - qtA;
    const int q0A = qtA * 16, q0B = qtB * 16;
    const int countA = g + 1, countB = 32 - g;
    const unsigned short* Kb = Kr + (size_t)bh * SEQ * DK;
    const unsigned short* Vb = Vt + (size_t)bh * DK * SEQ;

    const unsigned short* QbA = Qr + ((size_t)bh * SEQ + q0A) * DK;
    const unsigned short* QbB = Qr + ((size_t)bh * SEQ + q0B) * DK;
    const short8 qfA0 = *(const short8*)(QbA + l15 * DK + quad * 8);
    const short8 qfA1 = *(const short8*)(QbA + l15 * DK + 32 + quad * 8);
    const short8 qfB0 = *(const short8*)(QbB + l15 * DK + quad * 8);
    const short8 qfB1 = *(const short8*)(QbB + l15 * DK + 32 + quad * 8);

    const int slot0 = wave * 128 + lane, slot1 = slot0 + 64;
    const int ck0 = slot0 >> 3, s0 = slot0 & 7;
    const int ck1 = slot1 >> 3, s1 = slot1 & 7;
    const unsigned short* kp0 = Kb + ck0 * 64 + (s0 ^ (ck0 & 7)) * 8;
    const unsigned short* kp1 = Kb + ck1 * 64 + (s1 ^ (ck1 & 7)) * 8;
    const unsigned short* vp0 = Vb + ck0 * 2048 + (s0 ^ (ck0 & 7)) * 8;
    const unsigned short* vp1 = Vb + ck1 * 2048 + (s1 ^ (ck1 & 7)) * 8;
    const int kb0 = wave * 1024, kb1 = kb0 + 512;

    unsigned short* PA = Pl + (wave * 2 + 0) * 1152;
    unsigned short* PB = Pl + (wave * 2 + 1) * 1152;

    const f32x4 z4 = {0.f, 0.f, 0.f, 0.f};
    f32x4 oA[4], oB[4];
#pragma unroll
    for (int d = 0; d < 4; d++) { oA[d] = z4; oB[d] = z4; }
    float liA = 0.f, liB = 0.f;
    const int myqA = q0A + l15, myqB = q0B + l15;
    const int xr = l15 & 7;

    GLOAD_LDS16(kp0, &KVl[0][kb0]);
    GLOAD_LDS16(kp1, &KVl[0][kb1]);
    GLOAD_LDS16(vp0, &KVl[0][4096 + kb0]);
    GLOAD_LDS16(vp1, &KVl[0][4096 + kb1]);
    kp0 += 4096; kp1 += 4096; vp0 += 64; vp1 += 64;

    for (int j = 0; j < countB; ++j) {
        const int bf = j & 1;
        const unsigned short* Kl = KVl[bf];
        const unsigned short* Vl = KVl[bf] + 4096;
        __syncthreads();
        if (j + 1 < countB) {
            GLOAD_LDS16(kp0, &KVl[bf ^ 1][kb0]);
            GLOAD_LDS16(kp1, &KVl[bf ^ 1][kb1]);
            GLOAD_LDS16(vp0, &KVl[bf ^ 1][4096 + kb0]);
            GLOAD_LDS16(vp1, &KVl[bf ^ 1][4096 + kb1]);
            kp0 += 4096; kp1 += 4096; vp0 += 64; vp1 += 64;
        }
        const int j0 = j * 64;
        short8 kf[4][2];
#pragma unroll
        for (int t = 0; t < 4; t++) {
            const unsigned short* kr = Kl + (t * 16 + l15) * 64;
            kf[t][0] = *(const short8*)(kr + (quad ^ xr) * 8);
            kf[t][1] = *(const short8*)(kr + ((4 + quad) ^ xr) * 8);
        }
        f32x4 stB[4];
#pragma unroll
        for (int t = 0; t < 4; t++)
            stB[t] = MFMA16(kf[t][1], qfB1, MFMA16(kf[t][0], qfB0, z4));
        const bool doA = (j < countA);
        if (doA) {
            f32x4 stA[4];
#pragma unroll
            for (int t = 0; t < 4; t++)
                stA[t] = MFMA16(kf[t][1], qfA1, MFMA16(kf[t][0], qfA0, z4));
            if (j == countA - 1) softmax_tile<true >(stA, liA, PA, l15, quad, j0, myqA);
            else                 softmax_tile<false>(stA, liA, PA, l15, quad, j0, myqA);
        }
        if (j == countB - 1) softmax_tile<true >(stB, liB, PB, l15, quad, j0, myqB);
        else                 softmax_tile<false>(stB, liB, PB, l15, quad, j0, myqB);
        WAIT_LDS();
        short8 vf[4][2];
#pragma unroll
        for (int dt = 0; dt < 4; dt++) {
            const unsigned short* vr = Vl + (dt * 16 + l15) * 64;
            vf[dt][0] = *(const short8*)(vr + (quad ^ xr) * 8);
            vf[dt][1] = *(const short8*)(vr + ((4 + quad) ^ xr) * 8);
        }
        {
            const short8 pfB0 = *(const short8*)(PB + l15 * 72 + quad * 8);
            const short8 pfB1 = *(const short8*)(PB + l15 * 72 + 32 + quad * 8);
#pragma unroll
            for (int dt = 0; dt < 4; dt++)
                oB[dt] = MFMA16(vf[dt][1], pfB1, MFMA16(vf[dt][0], pfB0, oB[dt]));
        }
        if (doA) {
            const short8 pfA0 = *(const short8*)(PA + l15 * 72 + quad * 8);
            const short8 pfA1 = *(const short8*)(PA + l15 * 72 + 32 + quad * 8);
#pragma unroll
            for (int dt = 0; dt < 4; dt++)
                oA[dt] = MFMA16(vf[dt][1], pfA1, MFMA16(vf[dt][0], pfA0, oA[dt]));
        }
    }
    liA += __shfl_xor(liA, 16, 64); liA += __shfl_xor(liA, 32, 64);
    liB += __shfl_xor(liB, 16, 64); liB += __shfl_xor(liB, 32, 64);
    const float invA = 1.0f / liA, invB = 1.0f / liB;
#pragma unroll
    for (int dt = 0; dt < 4; dt++) {
        *(unsigned long long*)(PA + l15 * 72 + dt * 16 + quad * 4) =
            pack4bf(oA[dt][0] * invA, oA[dt][1] * invA, oA[dt][2] * invA, oA[dt][3] * invA);
        *(unsigned long long*)(PB + l15 * 72 + dt * 16 + quad * 4) =
            pack4bf(oB[dt][0] * invB, oB[dt][1] * invB, oB[dt][2] * invB, oB[dt][3] * invB);
    }
    WAIT_LDS();
    const int row = lane >> 2, seg = (lane & 3) * 8;
#pragma unroll
    for (int p = 0; p < 2; p++) {
        const int cs = seg + p * 32;
        const uint4 va = *(const uint4*)(PA + row * 72 + cs);
        *(uint4*)(ctx + ((size_t)b * SEQ + q0A + row) * DM + h * DK + cs) = va;
        const uint4 vb = *(const uint4*)(PB + row * 72 + cs);
        *(uint4*)(ctx + ((size_t)b * SEQ + q0B + row) * DM + h * DK + cs) = vb;
    }
}

extern "C" void kernel_launch(void* const* d_in, const int* in_sizes, int n_in,
                              void* d_out, int out_size, void* d_ws, size_t ws_size,
                              hipStream_t stream) {
    const float* x     = (const float*)d_in[0];
    const float* ln1_w = (const float*)d_in[1];
    const float* q_w   = (const float*)d_in[2];
    const float* k_w   = (const float*)d_in[3];
    const float* v_w   = (const float*)d_in[4];
    const float* o_w   = (const float*)d_in[5];
    const float* ln2_w = (const float*)d_in[6];
    const float* w1_w  = (const float*)d_in[7];
    const float* w3_w  = (const float*)d_in[8];
    const float* w2_w  = (const float*)d_in[9];
    const int*   tpos  = (const int*)d_in[10];
    float* out = (float*)d_out;
    char* ws = (char*)d_ws;

    unsigned short* Wqkv = (unsigned short*)(ws + 0);          // 6.29 MB
    unsigned short* Wo   = (unsigned short*)(ws + 6291456);    // 2.10 MB
    unsigned short* W13  = (unsigned short*)(ws + 8388608);    // 11.0 MB
    unsigned short* W2   = (unsigned short*)(ws + 19398656);   // 5.51 MB
    float*          X1   = (float*)(ws + 24903680);            // 16.78 MB (fp32)
    float*          ROPT = (float*)(ws + 24903680);            // alias: dead before X1 written
    char* base = ws + 41680896;
    unsigned short* H    = (unsigned short*)(base);             // 8.39 MB
    unsigned short* QR   = (unsigned short*)(base + 8388608);   // 8.39 MB
    unsigned short* KR   = (unsigned short*)(base + 16777216);  // 8.39 MB
    unsigned short* VT   = (unsigned short*)(base + 25165824);  // 8.39 MB
    unsigned short* CTX  = (unsigned short*)(base + 33554432);  // 8.39 MB
    unsigned short* H2   = (unsigned short*)(base);             // reuse H (dead after QKV)
    unsigned short* ACT  = (unsigned short*)(base + 41943040);  // 22.0 MB  (ends ~105.6 MB)

    prep_k<<<12160, 256, 0, stream>>>(q_w, k_w, v_w, o_w, w1_w, w3_w, w2_w,
                                      Wqkv, Wo, W13, W2);
    rope_tab_k<<<2048, 64, 0, stream>>>(tpos, ROPT);

    rmsnorm_k<<<4096, 256, 0, stream>>>(x, ln1_w, H);
    // QKV GEMM + fused RoPE + fused V-transpose (128x192, 2-phase, 2 blk/CU)
    gemm192<0><<<dim3(16, 32), 512, 0, stream>>>(H, Wqkv, QR, KR, VT, ROPT, 3072, 1024);
    attn_k<<<dim3(16, 32), 256, 0, stream>>>(QR, KR, VT, CTX);
    gemm_thin<<<dim3(16, 32), 256, 0, stream>>>(CTX, Wo, X1, x, 1024, 1024);
    rmsnorm_k<<<4096, 256, 0, stream>>>(X1, ln2_w, H2);
    // W13 GEMM + fused SwiGLU (w1/w3 row-interleaved, 128x192, 2-phase)
    gemm192<1><<<dim3(28, 32), 512, 0, stream>>>(H2, W13, ACT, nullptr, nullptr, nullptr, 5376, 1024);
    gemm_thin<<<dim3(16, 32), 256, 0, stream>>>(ACT, W2, out, X1, 1024, 2688);
}

// Round 11
// 408.455 us; speedup vs baseline: 1.0198x; 1.0198x over previous
//
#include <hip/hip_runtime.h>
#include <cstdint>

#define DM   1024
#define NH   16
#define DK   64
#define DFF  2688
#define SEQ  2048
#define BB   2
#define MTOT (BB*SEQ)   // 4096

typedef __attribute__((ext_vector_type(8))) short short8;
typedef __attribute__((ext_vector_type(4))) float f32x4;

typedef const __attribute__((address_space(1))) void* gaddr_t;
typedef __attribute__((address_space(3))) void* laddr_t;
#define GLOAD_LDS16(g, l) __builtin_amdgcn_global_load_lds((gaddr_t)(g), (laddr_t)(l), 16, 0, 0)
#define MFMA16(a, b, c) __builtin_amdgcn_mfma_f32_16x16x32_bf16((a), (b), (c), 0, 0, 0)
#define WAIT_LDS() __builtin_amdgcn_s_waitcnt(0xc07f)   // lgkmcnt(0) only

// counted-vmcnt sync primitives (r6/r8-proven correct).  Raw s_barrier does
// NOT drain vmcnt (unlike __syncthreads) -- loads stay in flight across it.
#define VMCNT(n) asm volatile("s_waitcnt vmcnt(" #n ")" ::: "memory")
#define BAR() do { asm volatile("" ::: "memory"); \
                   __builtin_amdgcn_s_barrier();  \
                   asm volatile("" ::: "memory"); } while (0)

__device__ __forceinline__ float bf2f(unsigned short u) {
    union { unsigned int i; float f; } v; v.i = ((unsigned int)u) << 16; return v.f;
}
__device__ __forceinline__ unsigned short f2bf(float f) {
    union { float f; unsigned int i; } v; v.f = f;
    unsigned int r = v.i + 0x7fffu + ((v.i >> 16) & 1u);
    return (unsigned short)(r >> 16);
}
__device__ __forceinline__ unsigned long long pack4bf(float a, float b, float c, float d) {
    return (unsigned long long)f2bf(a) | ((unsigned long long)f2bf(b) << 16)
         | ((unsigned long long)f2bf(c) << 32) | ((unsigned long long)f2bf(d) << 48);
}

// XCD-banded block bijection for gemm_thin (requires gridDim.y == 32).
__device__ __forceinline__ void band_swizzle(int& bx, int& by) {
    const int gx = gridDim.x;
    const int lin = blockIdx.y * gx + blockIdx.x;
    const int xcd = lin & 7, k = lin >> 3;
    by = xcd * 4 + (k & 3);
    bx = k >> 2;
}

// ---------------- fused fp32->bf16 weight convert (all 7 weights, 1 launch) ----
__global__ __launch_bounds__(256)
void prep_k(const float* __restrict__ q_w, const float* __restrict__ k_w,
            const float* __restrict__ v_w, const float* __restrict__ o_w,
            const float* __restrict__ w1_w, const float* __restrict__ w3_w,
            const float* __restrict__ w2_w,
            unsigned short* __restrict__ Wqkv, unsigned short* __restrict__ Wo,
            unsigned short* __restrict__ W13, unsigned short* __restrict__ W2) {
    const int blk = blockIdx.x;
    const float* src; unsigned short* dst; int cols, rmul, roff, i;
    if (blk < 4096) {
        const int rr = blk >> 10;
        i = (blk & 1023) * 256 + threadIdx.x;
        cols = 1024; rmul = 1;
        if (rr == 0)      { src = q_w; dst = Wqkv; roff = 0; }
        else if (rr == 1) { src = k_w; dst = Wqkv; roff = 1024; }
        else if (rr == 2) { src = v_w; dst = Wqkv; roff = 2048; }
        else              { src = o_w; dst = Wo;   roff = 0; }
    } else if (blk < 6784) {
        i = (blk - 4096) * 256 + threadIdx.x; src = w1_w; dst = W13; cols = 1024; rmul = 2; roff = 0;
    } else if (blk < 9472) {
        i = (blk - 6784) * 256 + threadIdx.x; src = w3_w; dst = W13; cols = 1024; rmul = 2; roff = 1;
    } else {
        i = (blk - 9472) * 256 + threadIdx.x; src = w2_w; dst = W2;  cols = 2688; rmul = 1; roff = 0;
    }
    const int e = i * 4;
    const int r = e / cols, c = e - r * cols;
    const float4 v = *(const float4*)(src + e);
    ushort4 o;
    o.x = f2bf(v.x); o.y = f2bf(v.y); o.z = f2bf(v.z); o.w = f2bf(v.w);
    *(ushort4*)(dst + (size_t)(r * rmul + roff) * cols + c) = o;
}

// ---------------- RMSNorm (row of 1024), fp32 in -> bf16 out -------------------
__global__ __launch_bounds__(256)
void rmsnorm_k(const float* __restrict__ x, const float* __restrict__ w,
               unsigned short* __restrict__ out) {
    const int row = blockIdx.x;
    const int tid = threadIdx.x;
    const float4 v = ((const float4*)(x + (size_t)row * DM))[tid];
    float ss = v.x * v.x + v.y * v.y + v.z * v.z + v.w * v.w;
#pragma unroll
    for (int off = 32; off > 0; off >>= 1) ss += __shfl_down(ss, off, 64);
    __shared__ float sred[4];
    const int wave = tid >> 6, lane = tid & 63;
    if (lane == 0) sred[wave] = ss;
    __syncthreads();
    const float tot = sred[0] + sred[1] + sred[2] + sred[3];
    const float rinv = rsqrtf(tot * (1.0f / DM) + 1e-5f);
    const float4 wv = ((const float4*)w)[tid];
    ushort4 o;
    o.x = f2bf(v.x * wv.x * rinv);
    o.y = f2bf(v.y * wv.y * rinv);
    o.z = f2bf(v.z * wv.z * rinv);
    o.w = f2bf(v.w * wv.w * rinv);
    ((ushort4*)(out + (size_t)row * DM))[tid] = o;
}

// ---------------- rope table (r11: 256-thread blocks, 4 positions each) --------
__global__ __launch_bounds__(256)
void rope_tab_k(const int* __restrict__ pos, float* __restrict__ tab) {
    const int tid = threadIdx.x;
    const int s = blockIdx.x * 4 + (tid >> 6);
    const int t = tid & 63;
    const int kk = t & 31;
    const float ang = (float)pos[s] * __expf(-0.28782313662f * (float)kk); // 10000^(-kk/32)
    tab[s * 64 + t] = (t < 32) ? cosf(ang) : sinf(ang);
}

// ======== 256x192 GEMM: BK=64, 8 waves, 4-phase interleave + reg-pipelined
// A-fragments (r9 BEST -- r11 keeps byte-identical).  Per K-tile: preamble
// stages A(t+1) -> VMCNT(4) -> BAR rendezvous; 4 phases of {af prefetch for
// p+1 (ping-pong regs) || B(t+1) staging under phase 1 || 12 MFMA w/ setprio
// || BAR}.  Ledger: entering iter t, 7 loads (tile t: A4+B3) outstanding;
// vmcnt(4) proves tile t landed while A(t+1) stays in flight; iter-end BAR
// covers WAR on buffer reuse.  Summation order per element identical to r0
// -> bit-identical output.
// Tile 256x192: QKV grid 256 blocks = exactly 1 round; FFN 448 = 1.75 rounds.
// Transposed acc: lane holds row r=m0+wr+m*16+l15, cols cc..cc+3 (consecutive)
// EPI 0: fused RoPE epilogue -> QR/KR/VT   EPI 1: fused SiLU -> ACT (N/2 cols)
template <int EPI>
__global__ __launch_bounds__(512)
void gemm256(const unsigned short* __restrict__ A,
             const unsigned short* __restrict__ B,
             unsigned short* __restrict__ O0,   // EPI0: QR   EPI1: ACT
             unsigned short* __restrict__ O1,   // EPI0: KR
             unsigned short* __restrict__ O2,   // EPI0: VT
             const float* __restrict__ ROPT,
             int N, int K) {
    __shared__ unsigned short As[2][16384];  // [8 koct][256 row][8 shorts] = 32 KB each
    __shared__ unsigned short Bs[2][12288];  // [8 koct][192 row][8 shorts] = 24 KB each
    const int tid = threadIdx.x;
    const int wave = tid >> 6, lane = tid & 63;
    const int l15 = lane & 15, quad = lane >> 4;

    // bijective XCD-chunked swizzle (nwg % 8 == 0: 256 / 448)
    const int gx = gridDim.x;
    const int nwg = gx * gridDim.y;
    const int lin = blockIdx.y * gx + blockIdx.x;
    const int swz = (lin & 7) * (nwg >> 3) + (lin >> 3);
    const int bx = swz % gx, by = swz / gx;
    const int m0 = by * 256, n0 = bx * 192;
    const int wr = (wave >> 2) * 128, wc = (wave & 3) * 48;

    const f32x4 z4 = {0.f, 0.f, 0.f, 0.f};
    f32x4 acc[8][3];
#pragma unroll
    for (int m = 0; m < 8; m++)
#pragma unroll
        for (int n = 0; n < 3; n++) acc[m][n] = z4;

    // staging: A = 2048 slots (4/thread, koct=s>>8,row=s&255);
    //          B = 1536 slots (3/thread, koct=s/192,row=s%192); 16 B/slot
    const unsigned short* pa[4];
    int la[4];
#pragma unroll
    for (int r = 0; r < 4; r++) {
        const int s = r * 512 + tid;
        pa[r] = A + (size_t)(m0 + (s & 255)) * K + (s >> 8) * 8;
        la[r] = (r * 512 + wave * 64) * 8;    // wave-uniform base; +lane*16B by HW
    }
    const unsigned short* pb[3];
    int lb[3];
#pragma unroll
    for (int r = 0; r < 3; r++) {
        const int s = r * 512 + tid;
        const int bk = s / 192, br = s - bk * 192;
        pb[r] = B + (size_t)(n0 + br) * K + bk * 8;
        lb[r] = (r * 512 + wave * 64) * 8;
    }

    const int nt = K >> 6;   // 16 K-tiles at K=1024

    // prologue: issue tile 0 stages (no drain -- iter 0's vmcnt handles it)
#pragma unroll
    for (int r = 0; r < 4; r++) { GLOAD_LDS16(pa[r], &As[0][la[r]]); pa[r] += 64; }
#pragma unroll
    for (int r = 0; r < 3; r++) { GLOAD_LDS16(pb[r], &Bs[0][lb[r]]); pb[r] += 64; }

    int cur = 0;
    for (int t = 0; t < nt; ++t) {
        const int nb = cur ^ 1;
        // ---- phase 0 preamble: stage A(t+1), counted wait, rendezvous ----
        if (t + 1 < nt) {
#pragma unroll
            for (int r = 0; r < 4; r++) { GLOAD_LDS16(pa[r], &As[nb][la[r]]); pa[r] += 64; }
            VMCNT(4);      // tile t's 7 landed; A(t+1)'s 4 stay in flight
        } else {
            VMCNT(0);      // tail: drain
        }
        BAR();             // rendezvous: everyone's tile-t stores visible

        short8 bg[3][2];   // B fragments: read once per K-tile, live all phases
#pragma unroll
        for (int n = 0; n < 3; n++)
#pragma unroll
            for (int kk = 0; kk < 2; kk++)
                bg[n][kk] = *(const short8*)(&Bs[cur][((quad + 4 * kk) * 192 + wc + n * 16 + l15) * 8]);

        // A-fragment ping-pong: read m-pair 0 now; each phase prefetches p+1.
        short8 afA[2][2], afB[2][2];
#pragma unroll
        for (int m = 0; m < 2; m++)
#pragma unroll
            for (int kk = 0; kk < 2; kk++)
                afA[m][kk] = *(const short8*)(&As[cur][((quad + 4 * kk) * 256 + wr + m * 16 + l15) * 8]);

#pragma unroll
        for (int p = 0; p < 4; ++p) {
            short8 (&afC)[2][2] = (p & 1) ? afB : afA;   // consumed this phase
            short8 (&afN)[2][2] = (p & 1) ? afA : afB;   // prefetched for p+1
            if (p < 3) {
#pragma unroll
                for (int m = 0; m < 2; m++)
#pragma unroll
                    for (int kk = 0; kk < 2; kk++)
                        afN[m][kk] = *(const short8*)(&As[cur][((quad + 4 * kk) * 256 + wr + ((p + 1) * 2 + m) * 16 + l15) * 8]);
            }
            if (p == 1 && t + 1 < nt) {      // stage B(t+1) under phase-1 compute
#pragma unroll
                for (int r = 0; r < 3; r++) { GLOAD_LDS16(pb[r], &Bs[nb][lb[r]]); pb[r] += 64; }
            }
            __builtin_amdgcn_s_setprio(1);
#pragma unroll
            for (int m = 0; m < 2; m++)
#pragma unroll
                for (int n = 0; n < 3; n++)
#pragma unroll
                    for (int kk = 0; kk < 2; kk++)
                        acc[p * 2 + m][n] = MFMA16(bg[n][kk], afC[m][kk], acc[p * 2 + m][n]);
            __builtin_amdgcn_s_setprio(0);
            BAR();         // phase-lock; final one doubles as iter-end WAR fence
        }
        cur = nb;
    }

#pragma unroll
    for (int m = 0; m < 8; m++) {
        const int r = m0 + wr + m * 16 + l15;     // token row
        if (EPI == 0) {
            const int b = r >> 11, s = r & (SEQ - 1);
            const float* rt = ROPT + s * 64;
#pragma unroll
            for (int n = 0; n < 3; n++) {
                const int cb = n0 + wc + n * 16;          // uniform per n (16-granular)
                const int sec = cb >> 10;                  // 0=Q 1=K 2=V
                const int h = (cb & 1023) >> 6;
                const int cc0 = (cb & 63) + quad * 4;      // even
                const f32x4 a = acc[m][n];
                if (sec < 2) {
                    const int p0 = cc0 >> 1;
                    const float cA = rt[p0],     sA = rt[32 + p0];
                    const float cB = rt[p0 + 1], sB = rt[32 + p0 + 1];
                    const float e0 = a[0] * cA - a[1] * sA;
                    const float o0 = a[0] * sA + a[1] * cA;
                    const float e1 = a[2] * cB - a[3] * sB;
                    const float o1 = a[2] * sB + a[3] * cB;
                    unsigned short* dst = (sec == 0) ? O0 : O1;
                    *(unsigned long long*)(dst + ((size_t)(b * NH + h) * SEQ + s) * DK + cc0) =
                        pack4bf(e0, o0, e1, o1);
                } else {
                    unsigned short* dst = O2 + ((size_t)(b * NH + h) * DK) * SEQ + s;
#pragma unroll
                    for (int tq = 0; tq < 4; tq++)
                        dst[(size_t)(cc0 + tq) * SEQ] = f2bf(a[tq]);
                }
            }
        } else {
#pragma unroll
            for (int n = 0; n < 3; n++) {
                const int cc = n0 + wc + n * 16 + quad * 4;   // even
                const f32x4 a = acc[m][n];
                const float s1 = a[0] * a[1] / (1.f + __expf(-a[0]));
                const float s2 = a[2] * a[3] / (1.f + __expf(-a[2]));
                *(unsigned int*)(O0 + (size_t)r * (DFF) + (cc >> 1)) =
                    (unsigned int)f2bf(s1) | ((unsigned int)f2bf(s2) << 16);
            }
        }
    }
}

// ---------------- thin-N GEMM: 128x64 block, BK=64, 4 blocks/CU ----------------
// r7 version: XCD-banded swizzle (A-panel pinning).  EPI: fp32 out = acc + R.
__global__ __launch_bounds__(256, 4)
void gemm_thin(const unsigned short* __restrict__ A,
               const unsigned short* __restrict__ B,
               float* __restrict__ Cf,
               const float* __restrict__ R,
               int N, int K) {
    __shared__ unsigned short As[8192];
    __shared__ unsigned short Bs[4096];
    const int tid = threadIdx.x;
    const int wave = tid >> 6, lane = tid & 63;
    const int l15 = lane & 15, quad = lane >> 4;
    int bx, by;
    band_swizzle(bx, by);
    const int m0 = by * 128, n0 = bx * 64;
    const int wr = (wave & 1) * 64, wc = (wave >> 1) * 32;

    const f32x4 z4 = {0.f, 0.f, 0.f, 0.f};
    f32x4 acc[4][2];
#pragma unroll
    for (int i = 0; i < 4; i++)
#pragma unroll
        for (int j = 0; j < 2; j++) acc[i][j] = z4;

    const unsigned short* ap[4];
    int al[4];
#pragma unroll
    for (int i = 0; i < 4; i++) {
        const int s = i * 256 + tid;
        ap[i] = A + (size_t)(m0 + (s & 127)) * K + (s >> 7) * 8;
        al[i] = (i * 256 + wave * 64) * 8;
    }
    const unsigned short* bp[2];
    int bl[2];
#pragma unroll
    for (int i = 0; i < 2; i++) {
        const int s = i * 256 + tid;
        bp[i] = B + (size_t)(n0 + (s & 63)) * K + (s >> 6) * 8;
        bl[i] = (i * 256 + wave * 64) * 8;
    }

    const int nk = K >> 6;
    for (int kc = 0; kc < nk; kc++) {
        __syncthreads();
#pragma unroll
        for (int i = 0; i < 4; i++) { GLOAD_LDS16(ap[i], &As[al[i]]); ap[i] += 64; }
#pragma unroll
        for (int i = 0; i < 2; i++) { GLOAD_LDS16(bp[i], &Bs[bl[i]]); bp[i] += 64; }
        __syncthreads();
#pragma unroll
        for (int h = 0; h < 2; h++) {
            short8 af[4], bg[2];
#pragma unroll
            for (int t = 0; t < 4; t++)
                af[t] = *(const short8*)(&As[((quad + 4 * h) * 128 + wr + t * 16 + l15) * 8]);
#pragma unroll
            for (int t = 0; t < 2; t++)
                bg[t] = *(const short8*)(&Bs[((quad + 4 * h) * 64 + wc + t * 16 + l15) * 8]);
#pragma unroll
            for (int i = 0; i < 4; i++)
#pragma unroll
                for (int j = 0; j < 2; j++)
                    acc[i][j] = MFMA16(bg[j], af[i], acc[i][j]);
        }
    }

#pragma unroll
    for (int i = 0; i < 4; i++) {
        const int r = m0 + wr + i * 16 + l15;
#pragma unroll
        for (int j = 0; j < 2; j++) {
            const int cc = n0 + wc + j * 16 + quad * 4;
            const size_t idx = (size_t)r * N + cc;
            const float4 rv = *(const float4*)(R + idx);
            float4 ov;
            ov.x = acc[i][j][0] + rv.x;
            ov.y = acc[i][j][1] + rv.y;
            ov.z = acc[i][j][2] + rv.z;
            ov.w = acc[i][j][3] + rv.w;
            *(float4*)(Cf + idx) = ov;
        }
    }
}

// ---------------- softmax tile update (max-free, per-lane partial li) ----------
template <bool MASK>
__device__ __forceinline__ void softmax_tile(f32x4 st[4], float& li, unsigned short* Pw,
                                             int l15, int quad, int j0, int myq) {
    float lsum = 0.f;
#pragma unroll
    for (int t = 0; t < 4; t++) {
#pragma unroll
        for (int r = 0; r < 4; r++) {
            float v = st[t][r] * 0.125f;
            if (MASK) {
                const int key = j0 + t * 16 + quad * 4 + r;
                if (key > myq) v = -1e30f;
            }
            const float p = __expf(v);
            st[t][r] = p;
            lsum += p;
        }
        *(unsigned long long*)(Pw + l15 * 72 + t * 16 + quad * 4) =
            pack4bf(st[t][0], st[t][1], st[t][2], st[t][3]);
    }
    li += lsum;
}

// ---------------- Flash attention v3: block-staged K/V, paired q-tiles ---------
// r11 delta: s_setprio(1) around the MFMA clusters (T5: measured +4-7% on
// attention structures with wave role diversity; blocks here are 2/CU and
// not cross-block barrier-locked).
__global__ __launch_bounds__(256, 2)
void attn_k(const unsigned short* __restrict__ Qr, const unsigned short* __restrict__ Kr,
            const unsigned short* __restrict__ Vt, unsigned short* __restrict__ ctx) {
    __shared__ unsigned short KVl[2][8192];
    __shared__ unsigned short Pl[4 * 2 * 1152];
    const int tid = threadIdx.x;
    const int wave = tid >> 6, lane = tid & 63;
    const int l15 = lane & 15, quad = lane >> 4;
    const int bh = blockIdx.y, b = bh >> 4, h = bh & 15;
    const int g = blockIdx.x;
    const int qtA = g * 4 + wave, qtB = 127 - qtA;
    const int q0A = qtA * 16, q0B = qtB * 16;
    const int countA = g + 1, countB = 32 - g;
    const unsigned short* Kb = Kr + (size_t)bh * SEQ * DK;
    const unsigned short* Vb = Vt + (size_t)bh * DK * SEQ;

    const unsigned short* QbA = Qr + ((size_t)bh * SEQ + q0A) * DK;
    const unsigned short* QbB = Qr + ((size_t)bh * SEQ + q0B) * DK;
    const short8 qfA0 = *(const short8*)(QbA + l15 * DK + quad * 8);
    const short8 qfA1 = *(const short8*)(QbA + l15 * DK + 32 + quad * 8);
    const short8 qfB0 = *(const short8*)(QbB + l15 * DK + quad * 8);
    const short8 qfB1 = *(const short8*)(QbB + l15 * DK + 32 + quad * 8);

    const int slot0 = wave * 128 + lane, slot1 = slot0 + 64;
    const int ck0 = slot0 >> 3, s0 = slot0 & 7;
    const int ck1 = slot1 >> 3, s1 = slot1 & 7;
    const unsigned short* kp0 = Kb + ck0 * 64 + (s0 ^ (ck0 & 7)) * 8;
    const unsigned short* kp1 = Kb + ck1 * 64 + (s1 ^ (ck1 & 7)) * 8;
    const unsigned short* vp0 = Vb + ck0 * 2048 + (s0 ^ (ck0 & 7)) * 8;
    const unsigned short* vp1 = Vb + ck1 * 2048 + (s1 ^ (ck1 & 7)) * 8;
    const int kb0 = wave * 1024, kb1 = kb0 + 512;

    unsigned short* PA = Pl + (wave * 2 + 0) * 1152;
    unsigned short* PB = Pl + (wave * 2 + 1) * 1152;

    const f32x4 z4 = {0.f, 0.f, 0.f, 0.f};
    f32x4 oA[4], oB[4];
#pragma unroll
    for (int d = 0; d < 4; d++) { oA[d] = z4; oB[d] = z4; }
    float liA = 0.f, liB = 0.f;
    const int myqA = q0A + l15, myqB = q0B + l15;
    const int xr = l15 & 7;

    GLOAD_LDS16(kp0, &KVl[0][kb0]);
    GLOAD_LDS16(kp1, &KVl[0][kb1]);
    GLOAD_LDS16(vp0, &KVl[0][4096 + kb0]);
    GLOAD_LDS16(vp1, &KVl[0][4096 + kb1]);
    kp0 += 4096; kp1 += 4096; vp0 += 64; vp1 += 64;

    for (int j = 0; j < countB; ++j) {
        const int bf = j & 1;
        const unsigned short* Kl = KVl[bf];
        const unsigned short* Vl = KVl[bf] + 4096;
        __syncthreads();
        if (j + 1 < countB) {
            GLOAD_LDS16(kp0, &KVl[bf ^ 1][kb0]);
            GLOAD_LDS16(kp1, &KVl[bf ^ 1][kb1]);
            GLOAD_LDS16(vp0, &KVl[bf ^ 1][4096 + kb0]);
            GLOAD_LDS16(vp1, &KVl[bf ^ 1][4096 + kb1]);
            kp0 += 4096; kp1 += 4096; vp0 += 64; vp1 += 64;
        }
        const int j0 = j * 64;
        short8 kf[4][2];
#pragma unroll
        for (int t = 0; t < 4; t++) {
            const unsigned short* kr = Kl + (t * 16 + l15) * 64;
            kf[t][0] = *(const short8*)(kr + (quad ^ xr) * 8);
            kf[t][1] = *(const short8*)(kr + ((4 + quad) ^ xr) * 8);
        }
        f32x4 stB[4];
        __builtin_amdgcn_s_setprio(1);
#pragma unroll
        for (int t = 0; t < 4; t++)
            stB[t] = MFMA16(kf[t][1], qfB1, MFMA16(kf[t][0], qfB0, z4));
        __builtin_amdgcn_s_setprio(0);
        const bool doA = (j < countA);
        if (doA) {
            f32x4 stA[4];
            __builtin_amdgcn_s_setprio(1);
#pragma unroll
            for (int t = 0; t < 4; t++)
                stA[t] = MFMA16(kf[t][1], qfA1, MFMA16(kf[t][0], qfA0, z4));
            __builtin_amdgcn_s_setprio(0);
            if (j == countA - 1) softmax_tile<true >(stA, liA, PA, l15, quad, j0, myqA);
            else                 softmax_tile<false>(stA, liA, PA, l15, quad, j0, myqA);
        }
        if (j == countB - 1) softmax_tile<true >(stB, liB, PB, l15, quad, j0, myqB);
        else                 softmax_tile<false>(stB, liB, PB, l15, quad, j0, myqB);
        WAIT_LDS();
        short8 vf[4][2];
#pragma unroll
        for (int dt = 0; dt < 4; dt++) {
            const unsigned short* vr = Vl + (dt * 16 + l15) * 64;
            vf[dt][0] = *(const short8*)(vr + (quad ^ xr) * 8);
            vf[dt][1] = *(const short8*)(vr + ((4 + quad) ^ xr) * 8);
        }
        {
            const short8 pfB0 = *(const short8*)(PB + l15 * 72 + quad * 8);
            const short8 pfB1 = *(const short8*)(PB + l15 * 72 + 32 + quad * 8);
            __builtin_amdgcn_s_setprio(1);
#pragma unroll
            for (int dt = 0; dt < 4; dt++)
                oB[dt] = MFMA16(vf[dt][1], pfB1, MFMA16(vf[dt][0], pfB0, oB[dt]));
            __builtin_amdgcn_s_setprio(0);
        }
        if (doA) {
            const short8 pfA0 = *(const short8*)(PA + l15 * 72 + quad * 8);
            const short8 pfA1 = *(const short8*)(PA + l15 * 72 + 32 + quad * 8);
            __builtin_amdgcn_s_setprio(1);
#pragma unroll
            for (int dt = 0; dt < 4; dt++)
                oA[dt] = MFMA16(vf[dt][1], pfA1, MFMA16(vf[dt][0], pfA0, oA[dt]));
            __builtin_amdgcn_s_setprio(0);
        }
    }
    liA += __shfl_xor(liA, 16, 64); liA += __shfl_xor(liA, 32, 64);
    liB += __shfl_xor(liB, 16, 64); liB += __shfl_xor(liB, 32, 64);
    const float invA = 1.0f / liA, invB = 1.0f / liB;
#pragma unroll
    for (int dt = 0; dt < 4; dt++) {
        *(unsigned long long*)(PA + l15 * 72 + dt * 16 + quad * 4) =
            pack4bf(oA[dt][0] * invA, oA[dt][1] * invA, oA[dt][2] * invA, oA[dt][3] * invA);
        *(unsigned long long*)(PB + l15 * 72 + dt * 16 + quad * 4) =
            pack4bf(oB[dt][0] * invB, oB[dt][1] * invB, oB[dt][2] * invB, oB[dt][3] * invB);
    }
    WAIT_LDS();
    const int row = lane >> 2, seg = (lane & 3) * 8;
#pragma unroll
    for (int p = 0; p < 2; p++) {
        const int cs = seg + p * 32;
        const uint4 va = *(const uint4*)(PA + row * 72 + cs);
        *(uint4*)(ctx + ((size_t)b * SEQ + q0A + row) * DM + h * DK + cs) = va;
        const uint4 vb = *(const uint4*)(PB + row * 72 + cs);
        *(uint4*)(ctx + ((size_t)b * SEQ + q0B + row) * DM + h * DK + cs) = vb;
    }
}

extern "C" void kernel_launch(void* const* d_in, const int* in_sizes, int n_in,
                              void* d_out, int out_size, void* d_ws, size_t ws_size,
                              hipStream_t stream) {
    const float* x     = (const float*)d_in[0];
    const float* ln1_w = (const float*)d_in[1];
    const float* q_w   = (const float*)d_in[2];
    const float* k_w   = (const float*)d_in[3];
    const float* v_w   = (const float*)d_in[4];
    const float* o_w   = (const float*)d_in[5];
    const float* ln2_w = (const float*)d_in[6];
    const float* w1_w  = (const float*)d_in[7];
    const float* w3_w  = (const float*)d_in[8];
    const float* w2_w  = (const float*)d_in[9];
    const int*   tpos  = (const int*)d_in[10];
    float* out = (float*)d_out;
    char* ws = (char*)d_ws;

    unsigned short* Wqkv = (unsigned short*)(ws + 0);          // 6.29 MB
    unsigned short* Wo   = (unsigned short*)(ws + 6291456);    // 2.10 MB
    unsigned short* W13  = (unsigned short*)(ws + 8388608);    // 11.0 MB
    unsigned short* W2   = (unsigned short*)(ws + 19398656);   // 5.51 MB
    float*          X1   = (float*)(ws + 24903680);            // 16.78 MB (fp32)
    float*          ROPT = (float*)(ws + 24903680);            // alias: dead before X1 written
    char* base = ws + 41680896;
    unsigned short* H    = (unsigned short*)(base);             // 8.39 MB
    unsigned short* QR   = (unsigned short*)(base + 8388608);   // 8.39 MB
    unsigned short* KR   = (unsigned short*)(base + 16777216);  // 8.39 MB
    unsigned short* VT   = (unsigned short*)(base + 25165824);  // 8.39 MB
    unsigned short* CTX  = (unsigned short*)(base + 33554432);  // 8.39 MB
    unsigned short* H2   = (unsigned short*)(base);             // reuse H (dead after QKV)
    unsigned short* ACT  = (unsigned short*)(base + 41943040);  // 22.0 MB  (ends ~105.6 MB)

    prep_k<<<12160, 256, 0, stream>>>(q_w, k_w, v_w, o_w, w1_w, w3_w, w2_w,
                                      Wqkv, Wo, W13, W2);
    rope_tab_k<<<512, 256, 0, stream>>>(tpos, ROPT);

    rmsnorm_k<<<4096, 256, 0, stream>>>(x, ln1_w, H);
    // QKV GEMM + fused RoPE + fused V-transpose (256x192, 4-phase + reg pipeline)
    gemm256<0><<<dim3(16, 16), 512, 0, stream>>>(H, Wqkv, QR, KR, VT, ROPT, 3072, 1024);
    attn_k<<<dim3(16, 32), 256, 0, stream>>>(QR, KR, VT, CTX);
    gemm_thin<<<dim3(16, 32), 256, 0, stream>>>(CTX, Wo, X1, x, 1024, 1024);
    rmsnorm_k<<<4096, 256, 0, stream>>>(X1, ln2_w, H2);
    // W13 GEMM + fused SwiGLU (w1/w3 row-interleaved, 256x192, 4-phase + pipeline)
    gemm256<1><<<dim3(28, 16), 512, 0, stream>>>(H2, W13, ACT, nullptr, nullptr, nullptr, 5376, 1024);
    gemm_thin<<<dim3(16, 32), 256, 0, stream>>>(ACT, W2, out, X1, 1024, 2688);
}

// Round 12
// 394.962 us; speedup vs baseline: 1.0546x; 1.0342x over previous
//
#include <hip/hip_runtime.h>
#include <cstdint>

#define DM   1024
#define NH   16
#define DK   64
#define DFF  2688
#define SEQ  2048
#define BB   2
#define MTOT (BB*SEQ)   // 4096

typedef __attribute__((ext_vector_type(8))) short short8;
typedef __attribute__((ext_vector_type(4))) float f32x4;

typedef const __attribute__((address_space(1))) void* gaddr_t;
typedef __attribute__((address_space(3))) void* laddr_t;
#define GLOAD_LDS16(g, l) __builtin_amdgcn_global_load_lds((gaddr_t)(g), (laddr_t)(l), 16, 0, 0)
#define MFMA16(a, b, c) __builtin_amdgcn_mfma_f32_16x16x32_bf16((a), (b), (c), 0, 0, 0)
#define WAIT_LDS() __builtin_amdgcn_s_waitcnt(0xc07f)   // lgkmcnt(0) only

// counted-vmcnt sync primitives (r6/r8/r9-proven correct).  Raw s_barrier does
// NOT drain vmcnt (unlike __syncthreads) -- loads stay in flight across it.
#define VMCNT(n) asm volatile("s_waitcnt vmcnt(" #n ")" ::: "memory")
#define BAR() do { asm volatile("" ::: "memory"); \
                   __builtin_amdgcn_s_barrier();  \
                   asm volatile("" ::: "memory"); } while (0)

__device__ __forceinline__ float bf2f(unsigned short u) {
    union { unsigned int i; float f; } v; v.i = ((unsigned int)u) << 16; return v.f;
}
__device__ __forceinline__ unsigned short f2bf(float f) {
    union { float f; unsigned int i; } v; v.f = f;
    unsigned int r = v.i + 0x7fffu + ((v.i >> 16) & 1u);
    return (unsigned short)(r >> 16);
}
__device__ __forceinline__ unsigned long long pack4bf(float a, float b, float c, float d) {
    return (unsigned long long)f2bf(a) | ((unsigned long long)f2bf(b) << 16)
         | ((unsigned long long)f2bf(c) << 32) | ((unsigned long long)f2bf(d) << 48);
}

// ---------------- fused fp32->bf16 weight convert (all 7 weights, 1 launch) ----
__global__ __launch_bounds__(256)
void prep_k(const float* __restrict__ q_w, const float* __restrict__ k_w,
            const float* __restrict__ v_w, const float* __restrict__ o_w,
            const float* __restrict__ w1_w, const float* __restrict__ w3_w,
            const float* __restrict__ w2_w,
            unsigned short* __restrict__ Wqkv, unsigned short* __restrict__ Wo,
            unsigned short* __restrict__ W13, unsigned short* __restrict__ W2) {
    const int blk = blockIdx.x;
    const float* src; unsigned short* dst; int cols, rmul, roff, i;
    if (blk < 4096) {
        const int rr = blk >> 10;
        i = (blk & 1023) * 256 + threadIdx.x;
        cols = 1024; rmul = 1;
        if (rr == 0)      { src = q_w; dst = Wqkv; roff = 0; }
        else if (rr == 1) { src = k_w; dst = Wqkv; roff = 1024; }
        else if (rr == 2) { src = v_w; dst = Wqkv; roff = 2048; }
        else              { src = o_w; dst = Wo;   roff = 0; }
    } else if (blk < 6784) {
        i = (blk - 4096) * 256 + threadIdx.x; src = w1_w; dst = W13; cols = 1024; rmul = 2; roff = 0;
    } else if (blk < 9472) {
        i = (blk - 6784) * 256 + threadIdx.x; src = w3_w; dst = W13; cols = 1024; rmul = 2; roff = 1;
    } else {
        i = (blk - 9472) * 256 + threadIdx.x; src = w2_w; dst = W2;  cols = 2688; rmul = 1; roff = 0;
    }
    const int e = i * 4;
    const int r = e / cols, c = e - r * cols;
    const float4 v = *(const float4*)(src + e);
    ushort4 o;
    o.x = f2bf(v.x); o.y = f2bf(v.y); o.z = f2bf(v.z); o.w = f2bf(v.w);
    *(ushort4*)(dst + (size_t)(r * rmul + roff) * cols + c) = o;
}

// ---------------- RMSNorm (row of 1024), fp32 in -> bf16 out -------------------
__global__ __launch_bounds__(256)
void rmsnorm_k(const float* __restrict__ x, const float* __restrict__ w,
               unsigned short* __restrict__ out) {
    const int row = blockIdx.x;
    const int tid = threadIdx.x;
    const float4 v = ((const float4*)(x + (size_t)row * DM))[tid];
    float ss = v.x * v.x + v.y * v.y + v.z * v.z + v.w * v.w;
#pragma unroll
    for (int off = 32; off > 0; off >>= 1) ss += __shfl_down(ss, off, 64);
    __shared__ float sred[4];
    const int wave = tid >> 6, lane = tid & 63;
    if (lane == 0) sred[wave] = ss;
    __syncthreads();
    const float tot = sred[0] + sred[1] + sred[2] + sred[3];
    const float rinv = rsqrtf(tot * (1.0f / DM) + 1e-5f);
    const float4 wv = ((const float4*)w)[tid];
    ushort4 o;
    o.x = f2bf(v.x * wv.x * rinv);
    o.y = f2bf(v.y * wv.y * rinv);
    o.z = f2bf(v.z * wv.z * rinv);
    o.w = f2bf(v.w * wv.w * rinv);
    ((ushort4*)(out + (size_t)row * DM))[tid] = o;
}

// ---------------- rope table (256-thread blocks, 4 positions each) -------------
__global__ __launch_bounds__(256)
void rope_tab_k(const int* __restrict__ pos, float* __restrict__ tab) {
    const int tid = threadIdx.x;
    const int s = blockIdx.x * 4 + (tid >> 6);
    const int t = tid & 63;
    const int kk = t & 31;
    const float ang = (float)pos[s] * __expf(-0.28782313662f * (float)kk); // 10000^(-kk/32)
    tab[s * 64 + t] = (t < 32) ? cosf(ang) : sinf(ang);
}

// ======== 256x192 GEMM: BK=64, 8 waves, 4-phase interleave + reg-pipelined
// A-fragments (r9 BEST -- kept byte-identical).  Per K-tile: preamble stages
// A(t+1) -> VMCNT(4) -> BAR rendezvous; 4 phases of {af prefetch for p+1
// (ping-pong regs) || B(t+1) staging under phase 1 || 12 MFMA w/ setprio ||
// BAR}.  Ledger: entering iter t, 7 loads (tile t: A4+B3) outstanding;
// vmcnt(4) proves tile t landed while A(t+1) stays in flight; iter-end BAR
// covers WAR on buffer reuse.  Summation order per element identical to r0
// -> bit-identical output.
// Tile 256x192: QKV grid 256 blocks = exactly 1 round; FFN 448 = 1.75 rounds.
// Transposed acc: lane holds row r=m0+wr+m*16+l15, cols cc..cc+3 (consecutive)
// EPI 0: fused RoPE epilogue -> QR/KR/VT   EPI 1: fused SiLU -> ACT (N/2 cols)
template <int EPI>
__global__ __launch_bounds__(512)
void gemm256(const unsigned short* __restrict__ A,
             const unsigned short* __restrict__ B,
             unsigned short* __restrict__ O0,   // EPI0: QR   EPI1: ACT
             unsigned short* __restrict__ O1,   // EPI0: KR
             unsigned short* __restrict__ O2,   // EPI0: VT
             const float* __restrict__ ROPT,
             int N, int K) {
    __shared__ unsigned short As[2][16384];  // [8 koct][256 row][8 shorts] = 32 KB each
    __shared__ unsigned short Bs[2][12288];  // [8 koct][192 row][8 shorts] = 24 KB each
    const int tid = threadIdx.x;
    const int wave = tid >> 6, lane = tid & 63;
    const int l15 = lane & 15, quad = lane >> 4;

    // bijective XCD-chunked swizzle (nwg % 8 == 0: 256 / 448)
    const int gx = gridDim.x;
    const int nwg = gx * gridDim.y;
    const int lin = blockIdx.y * gx + blockIdx.x;
    const int swz = (lin & 7) * (nwg >> 3) + (lin >> 3);
    const int bx = swz % gx, by = swz / gx;
    const int m0 = by * 256, n0 = bx * 192;
    const int wr = (wave >> 2) * 128, wc = (wave & 3) * 48;

    const f32x4 z4 = {0.f, 0.f, 0.f, 0.f};
    f32x4 acc[8][3];
#pragma unroll
    for (int m = 0; m < 8; m++)
#pragma unroll
        for (int n = 0; n < 3; n++) acc[m][n] = z4;

    // staging: A = 2048 slots (4/thread, koct=s>>8,row=s&255);
    //          B = 1536 slots (3/thread, koct=s/192,row=s%192); 16 B/slot
    const unsigned short* pa[4];
    int la[4];
#pragma unroll
    for (int r = 0; r < 4; r++) {
        const int s = r * 512 + tid;
        pa[r] = A + (size_t)(m0 + (s & 255)) * K + (s >> 8) * 8;
        la[r] = (r * 512 + wave * 64) * 8;    // wave-uniform base; +lane*16B by HW
    }
    const unsigned short* pb[3];
    int lb[3];
#pragma unroll
    for (int r = 0; r < 3; r++) {
        const int s = r * 512 + tid;
        const int bk = s / 192, br = s - bk * 192;
        pb[r] = B + (size_t)(n0 + br) * K + bk * 8;
        lb[r] = (r * 512 + wave * 64) * 8;
    }

    const int nt = K >> 6;   // 16 K-tiles at K=1024

    // prologue: issue tile 0 stages (no drain -- iter 0's vmcnt handles it)
#pragma unroll
    for (int r = 0; r < 4; r++) { GLOAD_LDS16(pa[r], &As[0][la[r]]); pa[r] += 64; }
#pragma unroll
    for (int r = 0; r < 3; r++) { GLOAD_LDS16(pb[r], &Bs[0][lb[r]]); pb[r] += 64; }

    int cur = 0;
    for (int t = 0; t < nt; ++t) {
        const int nb = cur ^ 1;
        // ---- phase 0 preamble: stage A(t+1), counted wait, rendezvous ----
        if (t + 1 < nt) {
#pragma unroll
            for (int r = 0; r < 4; r++) { GLOAD_LDS16(pa[r], &As[nb][la[r]]); pa[r] += 64; }
            VMCNT(4);      // tile t's 7 landed; A(t+1)'s 4 stay in flight
        } else {
            VMCNT(0);      // tail: drain
        }
        BAR();             // rendezvous: everyone's tile-t stores visible

        short8 bg[3][2];   // B fragments: read once per K-tile, live all phases
#pragma unroll
        for (int n = 0; n < 3; n++)
#pragma unroll
            for (int kk = 0; kk < 2; kk++)
                bg[n][kk] = *(const short8*)(&Bs[cur][((quad + 4 * kk) * 192 + wc + n * 16 + l15) * 8]);

        // A-fragment ping-pong: read m-pair 0 now; each phase prefetches p+1.
        short8 afA[2][2], afB[2][2];
#pragma unroll
        for (int m = 0; m < 2; m++)
#pragma unroll
            for (int kk = 0; kk < 2; kk++)
                afA[m][kk] = *(const short8*)(&As[cur][((quad + 4 * kk) * 256 + wr + m * 16 + l15) * 8]);

#pragma unroll
        for (int p = 0; p < 4; ++p) {
            short8 (&afC)[2][2] = (p & 1) ? afB : afA;   // consumed this phase
            short8 (&afN)[2][2] = (p & 1) ? afA : afB;   // prefetched for p+1
            if (p < 3) {
#pragma unroll
                for (int m = 0; m < 2; m++)
#pragma unroll
                    for (int kk = 0; kk < 2; kk++)
                        afN[m][kk] = *(const short8*)(&As[cur][((quad + 4 * kk) * 256 + wr + ((p + 1) * 2 + m) * 16 + l15) * 8]);
            }
            if (p == 1 && t + 1 < nt) {      // stage B(t+1) under phase-1 compute
#pragma unroll
                for (int r = 0; r < 3; r++) { GLOAD_LDS16(pb[r], &Bs[nb][lb[r]]); pb[r] += 64; }
            }
            __builtin_amdgcn_s_setprio(1);
#pragma unroll
            for (int m = 0; m < 2; m++)
#pragma unroll
                for (int n = 0; n < 3; n++)
#pragma unroll
                    for (int kk = 0; kk < 2; kk++)
                        acc[p * 2 + m][n] = MFMA16(bg[n][kk], afC[m][kk], acc[p * 2 + m][n]);
            __builtin_amdgcn_s_setprio(0);
            BAR();         // phase-lock; final one doubles as iter-end WAR fence
        }
        cur = nb;
    }

#pragma unroll
    for (int m = 0; m < 8; m++) {
        const int r = m0 + wr + m * 16 + l15;     // token row
        if (EPI == 0) {
            const int b = r >> 11, s = r & (SEQ - 1);
            const float* rt = ROPT + s * 64;
#pragma unroll
            for (int n = 0; n < 3; n++) {
                const int cb = n0 + wc + n * 16;          // uniform per n (16-granular)
                const int sec = cb >> 10;                  // 0=Q 1=K 2=V
                const int h = (cb & 1023) >> 6;
                const int cc0 = (cb & 63) + quad * 4;      // even
                const f32x4 a = acc[m][n];
                if (sec < 2) {
                    const int p0 = cc0 >> 1;
                    const float cA = rt[p0],     sA = rt[32 + p0];
                    const float cB = rt[p0 + 1], sB = rt[32 + p0 + 1];
                    const float e0 = a[0] * cA - a[1] * sA;
                    const float o0 = a[0] * sA + a[1] * cA;
                    const float e1 = a[2] * cB - a[3] * sB;
                    const float o1 = a[2] * sB + a[3] * cB;
                    unsigned short* dst = (sec == 0) ? O0 : O1;
                    *(unsigned long long*)(dst + ((size_t)(b * NH + h) * SEQ + s) * DK + cc0) =
                        pack4bf(e0, o0, e1, o1);
                } else {
                    unsigned short* dst = O2 + ((size_t)(b * NH + h) * DK) * SEQ + s;
#pragma unroll
                    for (int tq = 0; tq < 4; tq++)
                        dst[(size_t)(cc0 + tq) * SEQ] = f2bf(a[tq]);
                }
            }
        } else {
#pragma unroll
            for (int n = 0; n < 3; n++) {
                const int cc = n0 + wc + n * 16 + quad * 4;   // even
                const f32x4 a = acc[m][n];
                const float s1 = a[0] * a[1] / (1.f + __expf(-a[0]));
                const float s2 = a[2] * a[3] / (1.f + __expf(-a[2]));
                *(unsigned int*)(O0 + (size_t)r * (DFF) + (cc >> 1)) =
                    (unsigned int)f2bf(s1) | ((unsigned int)f2bf(s2) << 16);
            }
        }
    }
}

// ======== thin-N GEMM r12: 128x128 tile, BK=64, 8 waves, 2-phase counted ======
// Replaces the r0 serial 2-barrier 128x64 gemm_thin.  Geometry: grid
// (4096/128)x(1024/128) = 256 blocks = exactly one balanced round at
// 1 block/CU; staged bytes/CU drop 33-36% vs the old 128x64 2-blk/CU form.
// Machinery is the r9-proven family: counted VMCNT + raw BAR, staging
// interleaved under compute, setprio around MFMA clusters.
// Ledger: 4 loads/thread/K-tile (A2+B2, issue order A then B).  Entering
// iter t: 4 outstanding.  Preamble issues A(t+1)[2] -> 6 -> VMCNT(2) proves
// tile t's 4 landed (newer = A(t+1) only) -> BAR rendezvous.  Phase 0 issues
// B(t+1)[2] under compute.  Phase BAR x2; last doubles as WAR fence.
// Per phase: 4 ds_read (af m-pair) + 8 MFMA (2m x 2n x 2kk).
// Summation order per element identical to the old kernel (t asc, kk 0,1)
// -> bit-identical output.  EPI: fp32 out = acc + residual.
__global__ __launch_bounds__(512)
void gemm_thin(const unsigned short* __restrict__ A,
               const unsigned short* __restrict__ B,
               float* __restrict__ Cf,
               const float* __restrict__ R,
               int N, int K) {
    __shared__ unsigned short As[2][8192];   // [8 koct][128 row][8 shorts] = 16 KB each
    __shared__ unsigned short Bs[2][8192];
    const int tid = threadIdx.x;
    const int wave = tid >> 6, lane = tid & 63;
    const int l15 = lane & 15, quad = lane >> 4;

    // bijective XCD-chunked swizzle (nwg = 256, %8 == 0): XCD x owns 4
    // consecutive M-stripes (A-panel L2 pinning), walks N within.
    const int gx = gridDim.x;
    const int nwg = gx * gridDim.y;
    const int lin = blockIdx.y * gx + blockIdx.x;
    const int swz = (lin & 7) * (nwg >> 3) + (lin >> 3);
    const int bx = swz % gx, by = swz / gx;
    const int m0 = by * 128, n0 = bx * 128;
    const int wr = (wave >> 2) * 64, wc = (wave & 3) * 32;

    const f32x4 z4 = {0.f, 0.f, 0.f, 0.f};
    f32x4 acc[4][2];
#pragma unroll
    for (int m = 0; m < 4; m++)
#pragma unroll
        for (int n = 0; n < 2; n++) acc[m][n] = z4;

    // staging: A and B each 1024 slots (2/thread, koct=s>>7, row=s&127)
    const unsigned short* pa[2];
    const unsigned short* pb[2];
    int la[2], lb[2];
#pragma unroll
    for (int r = 0; r < 2; r++) {
        const int s = r * 512 + tid;
        pa[r] = A + (size_t)(m0 + (s & 127)) * K + (s >> 7) * 8;
        pb[r] = B + (size_t)(n0 + (s & 127)) * K + (s >> 7) * 8;
        la[r] = (r * 512 + wave * 64) * 8;    // wave-uniform base; +lane*16B by HW
        lb[r] = la[r];
    }

    const int nt = K >> 6;   // 16 (K=1024) or 42 (K=2688)

    // prologue: issue tile 0 stages (A then B; no drain -- iter 0's vmcnt)
#pragma unroll
    for (int r = 0; r < 2; r++) { GLOAD_LDS16(pa[r], &As[0][la[r]]); pa[r] += 64; }
#pragma unroll
    for (int r = 0; r < 2; r++) { GLOAD_LDS16(pb[r], &Bs[0][lb[r]]); pb[r] += 64; }

    int cur = 0;
    for (int t = 0; t < nt; ++t) {
        const int nb = cur ^ 1;
        if (t + 1 < nt) {
#pragma unroll
            for (int r = 0; r < 2; r++) { GLOAD_LDS16(pa[r], &As[nb][la[r]]); pa[r] += 64; }
            VMCNT(2);      // tile t's 4 landed; A(t+1)'s 2 stay in flight
        } else {
            VMCNT(0);      // tail: drain
        }
        BAR();             // rendezvous: everyone's tile-t stores visible

        short8 bg[2][2];   // B fragments: read once per K-tile, live both phases
#pragma unroll
        for (int n = 0; n < 2; n++)
#pragma unroll
            for (int kk = 0; kk < 2; kk++)
                bg[n][kk] = *(const short8*)(&Bs[cur][((quad + 4 * kk) * 128 + wc + n * 16 + l15) * 8]);

#pragma unroll
        for (int p = 0; p < 2; ++p) {
            if (p == 0 && t + 1 < nt) {      // stage B(t+1) under phase-0 compute
#pragma unroll
                for (int r = 0; r < 2; r++) { GLOAD_LDS16(pb[r], &Bs[nb][lb[r]]); pb[r] += 64; }
            }
            short8 af[2][2];
#pragma unroll
            for (int m = 0; m < 2; m++)
#pragma unroll
                for (int kk = 0; kk < 2; kk++)
                    af[m][kk] = *(const short8*)(&As[cur][((quad + 4 * kk) * 128 + wr + (p * 2 + m) * 16 + l15) * 8]);
            __builtin_amdgcn_s_setprio(1);
#pragma unroll
            for (int m = 0; m < 2; m++)
#pragma unroll
                for (int n = 0; n < 2; n++)
#pragma unroll
                    for (int kk = 0; kk < 2; kk++)
                        acc[p * 2 + m][n] = MFMA16(bg[n][kk], af[m][kk], acc[p * 2 + m][n]);
            __builtin_amdgcn_s_setprio(0);
            BAR();         // phase-lock; final one doubles as iter-end WAR fence
        }
        cur = nb;
    }

#pragma unroll
    for (int i = 0; i < 4; i++) {
        const int r = m0 + wr + i * 16 + l15;
#pragma unroll
        for (int j = 0; j < 2; j++) {
            const int cc = n0 + wc + j * 16 + quad * 4;
            const size_t idx = (size_t)r * N + cc;
            const float4 rv = *(const float4*)(R + idx);
            float4 ov;
            ov.x = acc[i][j][0] + rv.x;
            ov.y = acc[i][j][1] + rv.y;
            ov.z = acc[i][j][2] + rv.z;
            ov.w = acc[i][j][3] + rv.w;
            *(float4*)(Cf + idx) = ov;
        }
    }
}

// ---------------- softmax tile update (max-free, per-lane partial li) ----------
template <bool MASK>
__device__ __forceinline__ void softmax_tile(f32x4 st[4], float& li, unsigned short* Pw,
                                             int l15, int quad, int j0, int myq) {
    float lsum = 0.f;
#pragma unroll
    for (int t = 0; t < 4; t++) {
#pragma unroll
        for (int r = 0; r < 4; r++) {
            float v = st[t][r] * 0.125f;
            if (MASK) {
                const int key = j0 + t * 16 + quad * 4 + r;
                if (key > myq) v = -1e30f;
            }
            const float p = __expf(v);
            st[t][r] = p;
            lsum += p;
        }
        *(unsigned long long*)(Pw + l15 * 72 + t * 16 + quad * 4) =
            pack4bf(st[t][0], st[t][1], st[t][2], st[t][3]);
    }
    li += lsum;
}

// ---------------- Flash attention v3: block-staged K/V, paired q-tiles ---------
__global__ __launch_bounds__(256, 2)
void attn_k(const unsigned short* __restrict__ Qr, const unsigned short* __restrict__ Kr,
            const unsigned short* __restrict__ Vt, unsigned short* __restrict__ ctx) {
    __shared__ unsigned short KVl[2][8192];
    __shared__ unsigned short Pl[4 * 2 * 1152];
    const int tid = threadIdx.x;
    const int wave = tid >> 6, lane = tid & 63;
    const int l15 = lane & 15, quad = lane >> 4;
    const int bh = blockIdx.y, b = bh >> 4, h = bh & 15;
    const int g = blockIdx.x;
    const int qtA = g * 4 + wave, qtB = 127 - qtA;
    const int q0A = qtA * 16, q0B = qtB * 16;
    const int countA = g + 1, countB = 32 - g;
    const unsigned short* Kb = Kr + (size_t)bh * SEQ * DK;
    const unsigned short* Vb = Vt + (size_t)bh * DK * SEQ;

    const unsigned short* QbA = Qr + ((size_t)bh * SEQ + q0A) * DK;
    const unsigned short* QbB = Qr + ((size_t)bh * SEQ + q0B) * DK;
    const short8 qfA0 = *(const short8*)(QbA + l15 * DK + quad * 8);
    const short8 qfA1 = *(const short8*)(QbA + l15 * DK + 32 + quad * 8);
    const short8 qfB0 = *(const short8*)(QbB + l15 * DK + quad * 8);
    const short8 qfB1 = *(const short8*)(QbB + l15 * DK + 32 + quad * 8);

    const int slot0 = wave * 128 + lane, slot1 = slot0 + 64;
    const int ck0 = slot0 >> 3, s0 = slot0 & 7;
    const int ck1 = slot1 >> 3, s1 = slot1 & 7;
    const unsigned short* kp0 = Kb + ck0 * 64 + (s0 ^ (ck0 & 7)) * 8;
    const unsigned short* kp1 = Kb + ck1 * 64 + (s1 ^ (ck1 & 7)) * 8;
    const unsigned short* vp0 = Vb + ck0 * 2048 + (s0 ^ (ck0 & 7)) * 8;
    const unsigned short* vp1 = Vb + ck1 * 2048 + (s1 ^ (ck1 & 7)) * 8;
    const int kb0 = wave * 1024, kb1 = kb0 + 512;

    unsigned short* PA = Pl + (wave * 2 + 0) * 1152;
    unsigned short* PB = Pl + (wave * 2 + 1) * 1152;

    const f32x4 z4 = {0.f, 0.f, 0.f, 0.f};
    f32x4 oA[4], oB[4];
#pragma unroll
    for (int d = 0; d < 4; d++) { oA[d] = z4; oB[d] = z4; }
    float liA = 0.f, liB = 0.f;
    const int myqA = q0A + l15, myqB = q0B + l15;
    const int xr = l15 & 7;

    GLOAD_LDS16(kp0, &KVl[0][kb0]);
    GLOAD_LDS16(kp1, &KVl[0][kb1]);
    GLOAD_LDS16(vp0, &KVl[0][4096 + kb0]);
    GLOAD_LDS16(vp1, &KVl[0][4096 + kb1]);
    kp0 += 4096; kp1 += 4096; vp0 += 64; vp1 += 64;

    for (int j = 0; j < countB; ++j) {
        const int bf = j & 1;
        const unsigned short* Kl = KVl[bf];
        const unsigned short* Vl = KVl[bf] + 4096;
        __syncthreads();
        if (j + 1 < countB) {
            GLOAD_LDS16(kp0, &KVl[bf ^ 1][kb0]);
            GLOAD_LDS16(kp1, &KVl[bf ^ 1][kb1]);
            GLOAD_LDS16(vp0, &KVl[bf ^ 1][4096 + kb0]);
            GLOAD_LDS16(vp1, &KVl[bf ^ 1][4096 + kb1]);
            kp0 += 4096; kp1 += 4096; vp0 += 64; vp1 += 64;
        }
        const int j0 = j * 64;
        short8 kf[4][2];
#pragma unroll
        for (int t = 0; t < 4; t++) {
            const unsigned short* kr = Kl + (t * 16 + l15) * 64;
            kf[t][0] = *(const short8*)(kr + (quad ^ xr) * 8);
            kf[t][1] = *(const short8*)(kr + ((4 + quad) ^ xr) * 8);
        }
        f32x4 stB[4];
        __builtin_amdgcn_s_setprio(1);
#pragma unroll
        for (int t = 0; t < 4; t++)
            stB[t] = MFMA16(kf[t][1], qfB1, MFMA16(kf[t][0], qfB0, z4));
        __builtin_amdgcn_s_setprio(0);
        const bool doA = (j < countA);
        if (doA) {
            f32x4 stA[4];
            __builtin_amdgcn_s_setprio(1);
#pragma unroll
            for (int t = 0; t < 4; t++)
                stA[t] = MFMA16(kf[t][1], qfA1, MFMA16(kf[t][0], qfA0, z4));
            __builtin_amdgcn_s_setprio(0);
            if (j == countA - 1) softmax_tile<true >(stA, liA, PA, l15, quad, j0, myqA);
            else                 softmax_tile<false>(stA, liA, PA, l15, quad, j0, myqA);
        }
        if (j == countB - 1) softmax_tile<true >(stB, liB, PB, l15, quad, j0, myqB);
        else                 softmax_tile<false>(stB, liB, PB, l15, quad, j0, myqB);
        WAIT_LDS();
        short8 vf[4][2];
#pragma unroll
        for (int dt = 0; dt < 4; dt++) {
            const unsigned short* vr = Vl + (dt * 16 + l15) * 64;
            vf[dt][0] = *(const short8*)(vr + (quad ^ xr) * 8);
            vf[dt][1] = *(const short8*)(vr + ((4 + quad) ^ xr) * 8);
        }
        {
            const short8 pfB0 = *(const short8*)(PB + l15 * 72 + quad * 8);
            const short8 pfB1 = *(const short8*)(PB + l15 * 72 + 32 + quad * 8);
            __builtin_amdgcn_s_setprio(1);
#pragma unroll
            for (int dt = 0; dt < 4; dt++)
                oB[dt] = MFMA16(vf[dt][1], pfB1, MFMA16(vf[dt][0], pfB0, oB[dt]));
            __builtin_amdgcn_s_setprio(0);
        }
        if (doA) {
            const short8 pfA0 = *(const short8*)(PA + l15 * 72 + quad * 8);
            const short8 pfA1 = *(const short8*)(PA + l15 * 72 + 32 + quad * 8);
            __builtin_amdgcn_s_setprio(1);
#pragma unroll
            for (int dt = 0; dt < 4; dt++)
                oA[dt] = MFMA16(vf[dt][1], pfA1, MFMA16(vf[dt][0], pfA0, oA[dt]));
            __builtin_amdgcn_s_setprio(0);
        }
    }
    liA += __shfl_xor(liA, 16, 64); liA += __shfl_xor(liA, 32, 64);
    liB += __shfl_xor(liB, 16, 64); liB += __shfl_xor(liB, 32, 64);
    const float invA = 1.0f / liA, invB = 1.0f / liB;
#pragma unroll
    for (int dt = 0; dt < 4; dt++) {
        *(unsigned long long*)(PA + l15 * 72 + dt * 16 + quad * 4) =
            pack4bf(oA[dt][0] * invA, oA[dt][1] * invA, oA[dt][2] * invA, oA[dt][3] * invA);
        *(unsigned long long*)(PB + l15 * 72 + dt * 16 + quad * 4) =
            pack4bf(oB[dt][0] * invB, oB[dt][1] * invB, oB[dt][2] * invB, oB[dt][3] * invB);
    }
    WAIT_LDS();
    const int row = lane >> 2, seg = (lane & 3) * 8;
#pragma unroll
    for (int p = 0; p < 2; p++) {
        const int cs = seg + p * 32;
        const uint4 va = *(const uint4*)(PA + row * 72 + cs);
        *(uint4*)(ctx + ((size_t)b * SEQ + q0A + row) * DM + h * DK + cs) = va;
        const uint4 vb = *(const uint4*)(PB + row * 72 + cs);
        *(uint4*)(ctx + ((size_t)b * SEQ + q0B + row) * DM + h * DK + cs) = vb;
    }
}

extern "C" void kernel_launch(void* const* d_in, const int* in_sizes, int n_in,
                              void* d_out, int out_size, void* d_ws, size_t ws_size,
                              hipStream_t stream) {
    const float* x     = (const float*)d_in[0];
    const float* ln1_w = (const float*)d_in[1];
    const float* q_w   = (const float*)d_in[2];
    const float* k_w   = (const float*)d_in[3];
    const float* v_w   = (const float*)d_in[4];
    const float* o_w   = (const float*)d_in[5];
    const float* ln2_w = (const float*)d_in[6];
    const float* w1_w  = (const float*)d_in[7];
    const float* w3_w  = (const float*)d_in[8];
    const float* w2_w  = (const float*)d_in[9];
    const int*   tpos  = (const int*)d_in[10];
    float* out = (float*)d_out;
    char* ws = (char*)d_ws;

    unsigned short* Wqkv = (unsigned short*)(ws + 0);          // 6.29 MB
    unsigned short* Wo   = (unsigned short*)(ws + 6291456);    // 2.10 MB
    unsigned short* W13  = (unsigned short*)(ws + 8388608);    // 11.0 MB
    unsigned short* W2   = (unsigned short*)(ws + 19398656);   // 5.51 MB
    float*          X1   = (float*)(ws + 24903680);            // 16.78 MB (fp32)
    float*          ROPT = (float*)(ws + 24903680);            // alias: dead before X1 written
    char* base = ws + 41680896;
    unsigned short* H    = (unsigned short*)(base);             // 8.39 MB
    unsigned short* QR   = (unsigned short*)(base + 8388608);   // 8.39 MB
    unsigned short* KR   = (unsigned short*)(base + 16777216);  // 8.39 MB
    unsigned short* VT   = (unsigned short*)(base + 25165824);  // 8.39 MB
    unsigned short* CTX  = (unsigned short*)(base + 33554432);  // 8.39 MB
    unsigned short* H2   = (unsigned short*)(base);             // reuse H (dead after QKV)
    unsigned short* ACT  = (unsigned short*)(base + 41943040);  // 22.0 MB  (ends ~105.6 MB)

    prep_k<<<12160, 256, 0, stream>>>(q_w, k_w, v_w, o_w, w1_w, w3_w, w2_w,
                                      Wqkv, Wo, W13, W2);
    rope_tab_k<<<512, 256, 0, stream>>>(tpos, ROPT);

    rmsnorm_k<<<4096, 256, 0, stream>>>(x, ln1_w, H);
    // QKV GEMM + fused RoPE + fused V-transpose (256x192, 4-phase + reg pipeline)
    gemm256<0><<<dim3(16, 16), 512, 0, stream>>>(H, Wqkv, QR, KR, VT, ROPT, 3072, 1024);
    attn_k<<<dim3(16, 32), 256, 0, stream>>>(QR, KR, VT, CTX);
    // attn-out projection (128x128, 2-phase counted, 256 blocks = 1 round)
    gemm_thin<<<dim3(8, 32), 512, 0, stream>>>(CTX, Wo, X1, x, 1024, 1024);
    rmsnorm_k<<<4096, 256, 0, stream>>>(X1, ln2_w, H2);
    // W13 GEMM + fused SwiGLU (w1/w3 row-interleaved, 256x192, 4-phase + pipeline)
    gemm256<1><<<dim3(28, 16), 512, 0, stream>>>(H2, W13, ACT, nullptr, nullptr, nullptr, 5376, 1024);
    // FFN down-projection (128x128, 2-phase counted, K=2688)
    gemm_thin<<<dim3(8, 32), 512, 0, stream>>>(ACT, W2, out, X1, 1024, 2688);
}

// Round 13
// 390.773 us; speedup vs baseline: 1.0659x; 1.0107x over previous
//
#include <hip/hip_runtime.h>
#include <cstdint>

#define DM   1024
#define NH   16
#define DK   64
#define DFF  2688
#define SEQ  2048
#define BB   2
#define MTOT (BB*SEQ)   // 4096

typedef __attribute__((ext_vector_type(8))) short short8;
typedef __attribute__((ext_vector_type(4))) float f32x4;

typedef const __attribute__((address_space(1))) void* gaddr_t;
typedef __attribute__((address_space(3))) void* laddr_t;
#define GLOAD_LDS16(g, l) __builtin_amdgcn_global_load_lds((gaddr_t)(g), (laddr_t)(l), 16, 0, 0)
#define MFMA16(a, b, c) __builtin_amdgcn_mfma_f32_16x16x32_bf16((a), (b), (c), 0, 0, 0)
#define WAIT_LDS() __builtin_amdgcn_s_waitcnt(0xc07f)   // lgkmcnt(0) only

// counted-vmcnt sync primitives (r6/r8/r9-proven correct).  Raw s_barrier does
// NOT drain vmcnt (unlike __syncthreads) -- loads stay in flight across it.
#define VMCNT(n) asm volatile("s_waitcnt vmcnt(" #n ")" ::: "memory")
#define BAR() do { asm volatile("" ::: "memory"); \
                   __builtin_amdgcn_s_barrier();  \
                   asm volatile("" ::: "memory"); } while (0)

__device__ __forceinline__ float bf2f(unsigned short u) {
    union { unsigned int i; float f; } v; v.i = ((unsigned int)u) << 16; return v.f;
}
__device__ __forceinline__ unsigned short f2bf(float f) {
    union { float f; unsigned int i; } v; v.f = f;
    unsigned int r = v.i + 0x7fffu + ((v.i >> 16) & 1u);
    return (unsigned short)(r >> 16);
}
__device__ __forceinline__ unsigned long long pack4bf(float a, float b, float c, float d) {
    return (unsigned long long)f2bf(a) | ((unsigned long long)f2bf(b) << 16)
         | ((unsigned long long)f2bf(c) << 32) | ((unsigned long long)f2bf(d) << 48);
}

// ======== r13: fused prologue -- weight convert + rope table + rmsnorm1 =======
// The three dependency-free pre-GEMM launches merged into one dispatch so
// their blocks co-schedule (serial ~20-25us incl. launch gaps -> ~max-stream).
// Block ranges: [0,12160) = prep (code byte-identical to old prep_k),
// [12160,12672) = rope table (4 positions/block), rest = rmsnorm rows.
__global__ __launch_bounds__(256)
void prologue_k(const float* __restrict__ q_w, const float* __restrict__ k_w,
                const float* __restrict__ v_w, const float* __restrict__ o_w,
                const float* __restrict__ w1_w, const float* __restrict__ w3_w,
                const float* __restrict__ w2_w,
                unsigned short* __restrict__ Wqkv, unsigned short* __restrict__ Wo,
                unsigned short* __restrict__ W13, unsigned short* __restrict__ W2,
                const int* __restrict__ pos, float* __restrict__ tab,
                const float* __restrict__ x, const float* __restrict__ ln1_w,
                unsigned short* __restrict__ H) {
    const int blk = blockIdx.x;
    const int tid = threadIdx.x;
    if (blk < 12160) {
        // ---- weight fp32->bf16 convert ----
        const float* src; unsigned short* dst; int cols, rmul, roff, i;
        if (blk < 4096) {
            const int rr = blk >> 10;
            i = (blk & 1023) * 256 + tid;
            cols = 1024; rmul = 1;
            if (rr == 0)      { src = q_w; dst = Wqkv; roff = 0; }
            else if (rr == 1) { src = k_w; dst = Wqkv; roff = 1024; }
            else if (rr == 2) { src = v_w; dst = Wqkv; roff = 2048; }
            else              { src = o_w; dst = Wo;   roff = 0; }
        } else if (blk < 6784) {
            i = (blk - 4096) * 256 + tid; src = w1_w; dst = W13; cols = 1024; rmul = 2; roff = 0;
        } else if (blk < 9472) {
            i = (blk - 6784) * 256 + tid; src = w3_w; dst = W13; cols = 1024; rmul = 2; roff = 1;
        } else {
            i = (blk - 9472) * 256 + tid; src = w2_w; dst = W2;  cols = 2688; rmul = 1; roff = 0;
        }
        const int e = i * 4;
        const int r = e / cols, c = e - r * cols;
        const float4 v = *(const float4*)(src + e);
        ushort4 o;
        o.x = f2bf(v.x); o.y = f2bf(v.y); o.z = f2bf(v.z); o.w = f2bf(v.w);
        *(ushort4*)(dst + (size_t)(r * rmul + roff) * cols + c) = o;
    } else if (blk < 12672) {
        // ---- rope table (4 positions per block) ----
        const int s = (blk - 12160) * 4 + (tid >> 6);
        const int t = tid & 63;
        const int kk = t & 31;
        const float ang = (float)pos[s] * __expf(-0.28782313662f * (float)kk); // 10000^(-kk/32)
        tab[s * 64 + t] = (t < 32) ? cosf(ang) : sinf(ang);
    } else {
        // ---- rmsnorm row (fp32 in -> bf16 out) ----
        const int row = blk - 12672;
        const float4 v = ((const float4*)(x + (size_t)row * DM))[tid];
        float ss = v.x * v.x + v.y * v.y + v.z * v.z + v.w * v.w;
#pragma unroll
        for (int off = 32; off > 0; off >>= 1) ss += __shfl_down(ss, off, 64);
        __shared__ float sred[4];
        const int wave = tid >> 6, lane = tid & 63;
        if (lane == 0) sred[wave] = ss;
        __syncthreads();
        const float tot = sred[0] + sred[1] + sred[2] + sred[3];
        const float rinv = rsqrtf(tot * (1.0f / DM) + 1e-5f);
        const float4 wv = ((const float4*)ln1_w)[tid];
        ushort4 o;
        o.x = f2bf(v.x * wv.x * rinv);
        o.y = f2bf(v.y * wv.y * rinv);
        o.z = f2bf(v.z * wv.z * rinv);
        o.w = f2bf(v.w * wv.w * rinv);
        ((ushort4*)(H + (size_t)row * DM))[tid] = o;
    }
}

// ---------------- RMSNorm (row of 1024), fp32 in -> bf16 out -------------------
__global__ __launch_bounds__(256)
void rmsnorm_k(const float* __restrict__ x, const float* __restrict__ w,
               unsigned short* __restrict__ out) {
    const int row = blockIdx.x;
    const int tid = threadIdx.x;
    const float4 v = ((const float4*)(x + (size_t)row * DM))[tid];
    float ss = v.x * v.x + v.y * v.y + v.z * v.z + v.w * v.w;
#pragma unroll
    for (int off = 32; off > 0; off >>= 1) ss += __shfl_down(ss, off, 64);
    __shared__ float sred[4];
    const int wave = tid >> 6, lane = tid & 63;
    if (lane == 0) sred[wave] = ss;
    __syncthreads();
    const float tot = sred[0] + sred[1] + sred[2] + sred[3];
    const float rinv = rsqrtf(tot * (1.0f / DM) + 1e-5f);
    const float4 wv = ((const float4*)w)[tid];
    ushort4 o;
    o.x = f2bf(v.x * wv.x * rinv);
    o.y = f2bf(v.y * wv.y * rinv);
    o.z = f2bf(v.z * wv.z * rinv);
    o.w = f2bf(v.w * wv.w * rinv);
    ((ushort4*)(out + (size_t)row * DM))[tid] = o;
}

// ======== 256x192 GEMM: BK=64, 8 waves, 4-phase interleave + reg-pipelined
// A-fragments (r9 BEST -- kept byte-identical).  Per K-tile: preamble stages
// A(t+1) -> VMCNT(4) -> BAR rendezvous; 4 phases of {af prefetch for p+1
// (ping-pong regs) || B(t+1) staging under phase 1 || 12 MFMA w/ setprio ||
// BAR}.  Ledger: entering iter t, 7 loads (tile t: A4+B3) outstanding;
// vmcnt(4) proves tile t landed while A(t+1) stays in flight; iter-end BAR
// covers WAR on buffer reuse.  Summation order per element identical to r0
// -> bit-identical output.
// Tile 256x192: QKV grid 256 blocks = exactly 1 round; FFN 448 = 1.75 rounds.
// Transposed acc: lane holds row r=m0+wr+m*16+l15, cols cc..cc+3 (consecutive)
// EPI 0: fused RoPE epilogue -> QR/KR/VT   EPI 1: fused SiLU -> ACT (N/2 cols)
template <int EPI>
__global__ __launch_bounds__(512)
void gemm256(const unsigned short* __restrict__ A,
             const unsigned short* __restrict__ B,
             unsigned short* __restrict__ O0,   // EPI0: QR   EPI1: ACT
             unsigned short* __restrict__ O1,   // EPI0: KR
             unsigned short* __restrict__ O2,   // EPI0: VT
             const float* __restrict__ ROPT,
             int N, int K) {
    __shared__ unsigned short As[2][16384];  // [8 koct][256 row][8 shorts] = 32 KB each
    __shared__ unsigned short Bs[2][12288];  // [8 koct][192 row][8 shorts] = 24 KB each
    const int tid = threadIdx.x;
    const int wave = tid >> 6, lane = tid & 63;
    const int l15 = lane & 15, quad = lane >> 4;

    // bijective XCD-chunked swizzle (nwg % 8 == 0: 256 / 448)
    const int gx = gridDim.x;
    const int nwg = gx * gridDim.y;
    const int lin = blockIdx.y * gx + blockIdx.x;
    const int swz = (lin & 7) * (nwg >> 3) + (lin >> 3);
    const int bx = swz % gx, by = swz / gx;
    const int m0 = by * 256, n0 = bx * 192;
    const int wr = (wave >> 2) * 128, wc = (wave & 3) * 48;

    const f32x4 z4 = {0.f, 0.f, 0.f, 0.f};
    f32x4 acc[8][3];
#pragma unroll
    for (int m = 0; m < 8; m++)
#pragma unroll
        for (int n = 0; n < 3; n++) acc[m][n] = z4;

    // staging: A = 2048 slots (4/thread, koct=s>>8,row=s&255);
    //          B = 1536 slots (3/thread, koct=s/192,row=s%192); 16 B/slot
    const unsigned short* pa[4];
    int la[4];
#pragma unroll
    for (int r = 0; r < 4; r++) {
        const int s = r * 512 + tid;
        pa[r] = A + (size_t)(m0 + (s & 255)) * K + (s >> 8) * 8;
        la[r] = (r * 512 + wave * 64) * 8;    // wave-uniform base; +lane*16B by HW
    }
    const unsigned short* pb[3];
    int lb[3];
#pragma unroll
    for (int r = 0; r < 3; r++) {
        const int s = r * 512 + tid;
        const int bk = s / 192, br = s - bk * 192;
        pb[r] = B + (size_t)(n0 + br) * K + bk * 8;
        lb[r] = (r * 512 + wave * 64) * 8;
    }

    const int nt = K >> 6;   // 16 K-tiles at K=1024

    // prologue: issue tile 0 stages (no drain -- iter 0's vmcnt handles it)
#pragma unroll
    for (int r = 0; r < 4; r++) { GLOAD_LDS16(pa[r], &As[0][la[r]]); pa[r] += 64; }
#pragma unroll
    for (int r = 0; r < 3; r++) { GLOAD_LDS16(pb[r], &Bs[0][lb[r]]); pb[r] += 64; }

    int cur = 0;
    for (int t = 0; t < nt; ++t) {
        const int nb = cur ^ 1;
        // ---- phase 0 preamble: stage A(t+1), counted wait, rendezvous ----
        if (t + 1 < nt) {
#pragma unroll
            for (int r = 0; r < 4; r++) { GLOAD_LDS16(pa[r], &As[nb][la[r]]); pa[r] += 64; }
            VMCNT(4);      // tile t's 7 landed; A(t+1)'s 4 stay in flight
        } else {
            VMCNT(0);      // tail: drain
        }
        BAR();             // rendezvous: everyone's tile-t stores visible

        short8 bg[3][2];   // B fragments: read once per K-tile, live all phases
#pragma unroll
        for (int n = 0; n < 3; n++)
#pragma unroll
            for (int kk = 0; kk < 2; kk++)
                bg[n][kk] = *(const short8*)(&Bs[cur][((quad + 4 * kk) * 192 + wc + n * 16 + l15) * 8]);

        // A-fragment ping-pong: read m-pair 0 now; each phase prefetches p+1.
        short8 afA[2][2], afB[2][2];
#pragma unroll
        for (int m = 0; m < 2; m++)
#pragma unroll
            for (int kk = 0; kk < 2; kk++)
                afA[m][kk] = *(const short8*)(&As[cur][((quad + 4 * kk) * 256 + wr + m * 16 + l15) * 8]);

#pragma unroll
        for (int p = 0; p < 4; ++p) {
            short8 (&afC)[2][2] = (p & 1) ? afB : afA;   // consumed this phase
            short8 (&afN)[2][2] = (p & 1) ? afA : afB;   // prefetched for p+1
            if (p < 3) {
#pragma unroll
                for (int m = 0; m < 2; m++)
#pragma unroll
                    for (int kk = 0; kk < 2; kk++)
                        afN[m][kk] = *(const short8*)(&As[cur][((quad + 4 * kk) * 256 + wr + ((p + 1) * 2 + m) * 16 + l15) * 8]);
            }
            if (p == 1 && t + 1 < nt) {      // stage B(t+1) under phase-1 compute
#pragma unroll
                for (int r = 0; r < 3; r++) { GLOAD_LDS16(pb[r], &Bs[nb][lb[r]]); pb[r] += 64; }
            }
            __builtin_amdgcn_s_setprio(1);
#pragma unroll
            for (int m = 0; m < 2; m++)
#pragma unroll
                for (int n = 0; n < 3; n++)
#pragma unroll
                    for (int kk = 0; kk < 2; kk++)
                        acc[p * 2 + m][n] = MFMA16(bg[n][kk], afC[m][kk], acc[p * 2 + m][n]);
            __builtin_amdgcn_s_setprio(0);
            BAR();         // phase-lock; final one doubles as iter-end WAR fence
        }
        cur = nb;
    }

#pragma unroll
    for (int m = 0; m < 8; m++) {
        const int r = m0 + wr + m * 16 + l15;     // token row
        if (EPI == 0) {
            const int b = r >> 11, s = r & (SEQ - 1);
            const float* rt = ROPT + s * 64;
#pragma unroll
            for (int n = 0; n < 3; n++) {
                const int cb = n0 + wc + n * 16;          // uniform per n (16-granular)
                const int sec = cb >> 10;                  // 0=Q 1=K 2=V
                const int h = (cb & 1023) >> 6;
                const int cc0 = (cb & 63) + quad * 4;      // even
                const f32x4 a = acc[m][n];
                if (sec < 2) {
                    const int p0 = cc0 >> 1;
                    const float cA = rt[p0],     sA = rt[32 + p0];
                    const float cB = rt[p0 + 1], sB = rt[32 + p0 + 1];
                    const float e0 = a[0] * cA - a[1] * sA;
                    const float o0 = a[0] * sA + a[1] * cA;
                    const float e1 = a[2] * cB - a[3] * sB;
                    const float o1 = a[2] * sB + a[3] * cB;
                    unsigned short* dst = (sec == 0) ? O0 : O1;
                    *(unsigned long long*)(dst + ((size_t)(b * NH + h) * SEQ + s) * DK + cc0) =
                        pack4bf(e0, o0, e1, o1);
                } else {
                    unsigned short* dst = O2 + ((size_t)(b * NH + h) * DK) * SEQ + s;
#pragma unroll
                    for (int tq = 0; tq < 4; tq++)
                        dst[(size_t)(cc0 + tq) * SEQ] = f2bf(a[tq]);
                }
            }
        } else {
#pragma unroll
            for (int n = 0; n < 3; n++) {
                const int cc = n0 + wc + n * 16 + quad * 4;   // even
                const f32x4 a = acc[m][n];
                const float s1 = a[0] * a[1] / (1.f + __expf(-a[0]));
                const float s2 = a[2] * a[3] / (1.f + __expf(-a[2]));
                *(unsigned int*)(O0 + (size_t)r * (DFF) + (cc >> 1)) =
                    (unsigned int)f2bf(s1) | ((unsigned int)f2bf(s2) << 16);
            }
        }
    }
}

// ======== thin-N GEMM: 128x128 tile, BK=64, 8 waves, 2-phase counted (r12) ====
// Grid (4096/128)x(1024/128) = 256 blocks = one balanced round at 1 block/CU.
// Ledger: 4 loads/thread/K-tile (A2+B2).  Preamble issues A(t+1)[2] ->
// VMCNT(2) -> BAR rendezvous.  Phase 0 issues B(t+1)[2] under compute.
// Per phase: 4 ds_read (af m-pair) + 8 MFMA.  Summation order unchanged ->
// bit-identical output.  EPI: fp32 out = acc + residual.
__global__ __launch_bounds__(512)
void gemm_thin(const unsigned short* __restrict__ A,
               const unsigned short* __restrict__ B,
               float* __restrict__ Cf,
               const float* __restrict__ R,
               int N, int K) {
    __shared__ unsigned short As[2][8192];   // [8 koct][128 row][8 shorts] = 16 KB each
    __shared__ unsigned short Bs[2][8192];
    const int tid = threadIdx.x;
    const int wave = tid >> 6, lane = tid & 63;
    const int l15 = lane & 15, quad = lane >> 4;

    // bijective XCD-chunked swizzle (nwg = 256, %8 == 0)
    const int gx = gridDim.x;
    const int nwg = gx * gridDim.y;
    const int lin = blockIdx.y * gx + blockIdx.x;
    const int swz = (lin & 7) * (nwg >> 3) + (lin >> 3);
    const int bx = swz % gx, by = swz / gx;
    const int m0 = by * 128, n0 = bx * 128;
    const int wr = (wave >> 2) * 64, wc = (wave & 3) * 32;

    const f32x4 z4 = {0.f, 0.f, 0.f, 0.f};
    f32x4 acc[4][2];
#pragma unroll
    for (int m = 0; m < 4; m++)
#pragma unroll
        for (int n = 0; n < 2; n++) acc[m][n] = z4;

    // staging: A and B each 1024 slots (2/thread, koct=s>>7, row=s&127)
    const unsigned short* pa[2];
    const unsigned short* pb[2];
    int la[2], lb[2];
#pragma unroll
    for (int r = 0; r < 2; r++) {
        const int s = r * 512 + tid;
        pa[r] = A + (size_t)(m0 + (s & 127)) * K + (s >> 7) * 8;
        pb[r] = B + (size_t)(n0 + (s & 127)) * K + (s >> 7) * 8;
        la[r] = (r * 512 + wave * 64) * 8;    // wave-uniform base; +lane*16B by HW
        lb[r] = la[r];
    }

    const int nt = K >> 6;   // 16 (K=1024) or 42 (K=2688)

    // prologue: issue tile 0 stages (A then B; no drain -- iter 0's vmcnt)
#pragma unroll
    for (int r = 0; r < 2; r++) { GLOAD_LDS16(pa[r], &As[0][la[r]]); pa[r] += 64; }
#pragma unroll
    for (int r = 0; r < 2; r++) { GLOAD_LDS16(pb[r], &Bs[0][lb[r]]); pb[r] += 64; }

    int cur = 0;
    for (int t = 0; t < nt; ++t) {
        const int nb = cur ^ 1;
        if (t + 1 < nt) {
#pragma unroll
            for (int r = 0; r < 2; r++) { GLOAD_LDS16(pa[r], &As[nb][la[r]]); pa[r] += 64; }
            VMCNT(2);      // tile t's 4 landed; A(t+1)'s 2 stay in flight
        } else {
            VMCNT(0);      // tail: drain
        }
        BAR();             // rendezvous: everyone's tile-t stores visible

        short8 bg[2][2];   // B fragments: read once per K-tile, live both phases
#pragma unroll
        for (int n = 0; n < 2; n++)
#pragma unroll
            for (int kk = 0; kk < 2; kk++)
                bg[n][kk] = *(const short8*)(&Bs[cur][((quad + 4 * kk) * 128 + wc + n * 16 + l15) * 8]);

#pragma unroll
        for (int p = 0; p < 2; ++p) {
            if (p == 0 && t + 1 < nt) {      // stage B(t+1) under phase-0 compute
#pragma unroll
                for (int r = 0; r < 2; r++) { GLOAD_LDS16(pb[r], &Bs[nb][lb[r]]); pb[r] += 64; }
            }
            short8 af[2][2];
#pragma unroll
            for (int m = 0; m < 2; m++)
#pragma unroll
                for (int kk = 0; kk < 2; kk++)
                    af[m][kk] = *(const short8*)(&As[cur][((quad + 4 * kk) * 128 + wr + (p * 2 + m) * 16 + l15) * 8]);
            __builtin_amdgcn_s_setprio(1);
#pragma unroll
            for (int m = 0; m < 2; m++)
#pragma unroll
                for (int n = 0; n < 2; n++)
#pragma unroll
                    for (int kk = 0; kk < 2; kk++)
                        acc[p * 2 + m][n] = MFMA16(bg[n][kk], af[m][kk], acc[p * 2 + m][n]);
            __builtin_amdgcn_s_setprio(0);
            BAR();         // phase-lock; final one doubles as iter-end WAR fence
        }
        cur = nb;
    }

#pragma unroll
    for (int i = 0; i < 4; i++) {
        const int r = m0 + wr + i * 16 + l15;
#pragma unroll
        for (int j = 0; j < 2; j++) {
            const int cc = n0 + wc + j * 16 + quad * 4;
            const size_t idx = (size_t)r * N + cc;
            const float4 rv = *(const float4*)(R + idx);
            float4 ov;
            ov.x = acc[i][j][0] + rv.x;
            ov.y = acc[i][j][1] + rv.y;
            ov.z = acc[i][j][2] + rv.z;
            ov.w = acc[i][j][3] + rv.w;
            *(float4*)(Cf + idx) = ov;
        }
    }
}

// ---------------- softmax tile update (max-free, per-lane partial li) ----------
template <bool MASK>
__device__ __forceinline__ void softmax_tile(f32x4 st[4], float& li, unsigned short* Pw,
                                             int l15, int quad, int j0, int myq) {
    float lsum = 0.f;
#pragma unroll
    for (int t = 0; t < 4; t++) {
#pragma unroll
        for (int r = 0; r < 4; r++) {
            float v = st[t][r] * 0.125f;
            if (MASK) {
                const int key = j0 + t * 16 + quad * 4 + r;
                if (key > myq) v = -1e30f;
            }
            const float p = __expf(v);
            st[t][r] = p;
            lsum += p;
        }
        *(unsigned long long*)(Pw + l15 * 72 + t * 16 + quad * 4) =
            pack4bf(st[t][0], st[t][1], st[t][2], st[t][3]);
    }
    li += lsum;
}

// ---------------- Flash attention v3: block-staged K/V, paired q-tiles ---------
__global__ __launch_bounds__(256, 2)
void attn_k(const unsigned short* __restrict__ Qr, const unsigned short* __restrict__ Kr,
            const unsigned short* __restrict__ Vt, unsigned short* __restrict__ ctx) {
    __shared__ unsigned short KVl[2][8192];
    __shared__ unsigned short Pl[4 * 2 * 1152];
    const int tid = threadIdx.x;
    const int wave = tid >> 6, lane = tid & 63;
    const int l15 = lane & 15, quad = lane >> 4;
    const int bh = blockIdx.y, b = bh >> 4, h = bh & 15;
    const int g = blockIdx.x;
    const int qtA = g * 4 + wave, qtB = 127 - qtA;
    const int q0A = qtA * 16, q0B = qtB * 16;
    const int countA = g + 1, countB = 32 - g;
    const unsigned short* Kb = Kr + (size_t)bh * SEQ * DK;
    const unsigned short* Vb = Vt + (size_t)bh * DK * SEQ;

    const unsigned short* QbA = Qr + ((size_t)bh * SEQ + q0A) * DK;
    const unsigned short* QbB = Qr + ((size_t)bh * SEQ + q0B) * DK;
    const short8 qfA0 = *(const short8*)(QbA + l15 * DK + quad * 8);
    const short8 qfA1 = *(const short8*)(QbA + l15 * DK + 32 + quad * 8);
    const short8 qfB0 = *(const short8*)(QbB + l15 * DK + quad * 8);
    const short8 qfB1 = *(const short8*)(QbB + l15 * DK + 32 + quad * 8);

    const int slot0 = wave * 128 + lane, slot1 = slot0 + 64;
    const int ck0 = slot0 >> 3, s0 = slot0 & 7;
    const int ck1 = slot1 >> 3, s1 = slot1 & 7;
    const unsigned short* kp0 = Kb + ck0 * 64 + (s0 ^ (ck0 & 7)) * 8;
    const unsigned short* kp1 = Kb + ck1 * 64 + (s1 ^ (ck1 & 7)) * 8;
    const unsigned short* vp0 = Vb + ck0 * 2048 + (s0 ^ (ck0 & 7)) * 8;
    const unsigned short* vp1 = Vb + ck1 * 2048 + (s1 ^ (ck1 & 7)) * 8;
    const int kb0 = wave * 1024, kb1 = kb0 + 512;

    unsigned short* PA = Pl + (wave * 2 + 0) * 1152;
    unsigned short* PB = Pl + (wave * 2 + 1) * 1152;

    const f32x4 z4 = {0.f, 0.f, 0.f, 0.f};
    f32x4 oA[4], oB[4];
#pragma unroll
    for (int d = 0; d < 4; d++) { oA[d] = z4; oB[d] = z4; }
    float liA = 0.f, liB = 0.f;
    const int myqA = q0A + l15, myqB = q0B + l15;
    const int xr = l15 & 7;

    GLOAD_LDS16(kp0, &KVl[0][kb0]);
    GLOAD_LDS16(kp1, &KVl[0][kb1]);
    GLOAD_LDS16(vp0, &KVl[0][4096 + kb0]);
    GLOAD_LDS16(vp1, &KVl[0][4096 + kb1]);
    kp0 += 4096; kp1 += 4096; vp0 += 64; vp1 += 64;

    for (int j = 0; j < countB; ++j) {
        const int bf = j & 1;
        const unsigned short* Kl = KVl[bf];
        const unsigned short* Vl = KVl[bf] + 4096;
        __syncthreads();
        if (j + 1 < countB) {
            GLOAD_LDS16(kp0, &KVl[bf ^ 1][kb0]);
            GLOAD_LDS16(kp1, &KVl[bf ^ 1][kb1]);
            GLOAD_LDS16(vp0, &KVl[bf ^ 1][4096 + kb0]);
            GLOAD_LDS16(vp1, &KVl[bf ^ 1][4096 + kb1]);
            kp0 += 4096; kp1 += 4096; vp0 += 64; vp1 += 64;
        }
        const int j0 = j * 64;
        short8 kf[4][2];
#pragma unroll
        for (int t = 0; t < 4; t++) {
            const unsigned short* kr = Kl + (t * 16 + l15) * 64;
            kf[t][0] = *(const short8*)(kr + (quad ^ xr) * 8);
            kf[t][1] = *(const short8*)(kr + ((4 + quad) ^ xr) * 8);
        }
        f32x4 stB[4];
        __builtin_amdgcn_s_setprio(1);
#pragma unroll
        for (int t = 0; t < 4; t++)
            stB[t] = MFMA16(kf[t][1], qfB1, MFMA16(kf[t][0], qfB0, z4));
        __builtin_amdgcn_s_setprio(0);
        const bool doA = (j < countA);
        if (doA) {
            f32x4 stA[4];
            __builtin_amdgcn_s_setprio(1);
#pragma unroll
            for (int t = 0; t < 4; t++)
                stA[t] = MFMA16(kf[t][1], qfA1, MFMA16(kf[t][0], qfA0, z4));
            __builtin_amdgcn_s_setprio(0);
            if (j == countA - 1) softmax_tile<true >(stA, liA, PA, l15, quad, j0, myqA);
            else                 softmax_tile<false>(stA, liA, PA, l15, quad, j0, myqA);
        }
        if (j == countB - 1) softmax_tile<true >(stB, liB, PB, l15, quad, j0, myqB);
        else                 softmax_tile<false>(stB, liB, PB, l15, quad, j0, myqB);
        WAIT_LDS();
        short8 vf[4][2];
#pragma unroll
        for (int dt = 0; dt < 4; dt++) {
            const unsigned short* vr = Vl + (dt * 16 + l15) * 64;
            vf[dt][0] = *(const short8*)(vr + (quad ^ xr) * 8);
            vf[dt][1] = *(const short8*)(vr + ((4 + quad) ^ xr) * 8);
        }
        {
            const short8 pfB0 = *(const short8*)(PB + l15 * 72 + quad * 8);
            const short8 pfB1 = *(const short8*)(PB + l15 * 72 + 32 + quad * 8);
            __builtin_amdgcn_s_setprio(1);
#pragma unroll
            for (int dt = 0; dt < 4; dt++)
                oB[dt] = MFMA16(vf[dt][1], pfB1, MFMA16(vf[dt][0], pfB0, oB[dt]));
            __builtin_amdgcn_s_setprio(0);
        }
        if (doA) {
            const short8 pfA0 = *(const short8*)(PA + l15 * 72 + quad * 8);
            const short8 pfA1 = *(const short8*)(PA + l15 * 72 + 32 + quad * 8);
            __builtin_amdgcn_s_setprio(1);
#pragma unroll
            for (int dt = 0; dt < 4; dt++)
                oA[dt] = MFMA16(vf[dt][1], pfA1, MFMA16(vf[dt][0], pfA0, oA[dt]));
            __builtin_amdgcn_s_setprio(0);
        }
    }
    liA += __shfl_xor(liA, 16, 64); liA += __shfl_xor(liA, 32, 64);
    liB += __shfl_xor(liB, 16, 64); liB += __shfl_xor(liB, 32, 64);
    const float invA = 1.0f / liA, invB = 1.0f / liB;
#pragma unroll
    for (int dt = 0; dt < 4; dt++) {
        *(unsigned long long*)(PA + l15 * 72 + dt * 16 + quad * 4) =
            pack4bf(oA[dt][0] * invA, oA[dt][1] * invA, oA[dt][2] * invA, oA[dt][3] * invA);
        *(unsigned long long*)(PB + l15 * 72 + dt * 16 + quad * 4) =
            pack4bf(oB[dt][0] * invB, oB[dt][1] * invB, oB[dt][2] * invB, oB[dt][3] * invB);
    }
    WAIT_LDS();
    const int row = lane >> 2, seg = (lane & 3) * 8;
#pragma unroll
    for (int p = 0; p < 2; p++) {
        const int cs = seg + p * 32;
        const uint4 va = *(const uint4*)(PA + row * 72 + cs);
        *(uint4*)(ctx + ((size_t)b * SEQ + q0A + row) * DM + h * DK + cs) = va;
        const uint4 vb = *(const uint4*)(PB + row * 72 + cs);
        *(uint4*)(ctx + ((size_t)b * SEQ + q0B + row) * DM + h * DK + cs) = vb;
    }
}

extern "C" void kernel_launch(void* const* d_in, const int* in_sizes, int n_in,
                              void* d_out, int out_size, void* d_ws, size_t ws_size,
                              hipStream_t stream) {
    const float* x     = (const float*)d_in[0];
    const float* ln1_w = (const float*)d_in[1];
    const float* q_w   = (const float*)d_in[2];
    const float* k_w   = (const float*)d_in[3];
    const float* v_w   = (const float*)d_in[4];
    const float* o_w   = (const float*)d_in[5];
    const float* ln2_w = (const float*)d_in[6];
    const float* w1_w  = (const float*)d_in[7];
    const float* w3_w  = (const float*)d_in[8];
    const float* w2_w  = (const float*)d_in[9];
    const int*   tpos  = (const int*)d_in[10];
    float* out = (float*)d_out;
    char* ws = (char*)d_ws;

    unsigned short* Wqkv = (unsigned short*)(ws + 0);          // 6.29 MB
    unsigned short* Wo   = (unsigned short*)(ws + 6291456);    // 2.10 MB
    unsigned short* W13  = (unsigned short*)(ws + 8388608);    // 11.0 MB
    unsigned short* W2   = (unsigned short*)(ws + 19398656);   // 5.51 MB
    float*          X1   = (float*)(ws + 24903680);            // 16.78 MB (fp32)
    float*          ROPT = (float*)(ws + 24903680);            // alias: dead before X1 written
    char* base = ws + 41680896;
    unsigned short* H    = (unsigned short*)(base);             // 8.39 MB
    unsigned short* QR   = (unsigned short*)(base + 8388608);   // 8.39 MB
    unsigned short* KR   = (unsigned short*)(base + 16777216);  // 8.39 MB
    unsigned short* VT   = (unsigned short*)(base + 25165824);  // 8.39 MB
    unsigned short* CTX  = (unsigned short*)(base + 33554432);  // 8.39 MB
    unsigned short* H2   = (unsigned short*)(base);             // reuse H (dead after QKV)
    unsigned short* ACT  = (unsigned short*)(base + 41943040);  // 22.0 MB  (ends ~105.6 MB)

    // fused prologue: weight convert + rope table + rmsnorm1 in one dispatch
    prologue_k<<<16768, 256, 0, stream>>>(q_w, k_w, v_w, o_w, w1_w, w3_w, w2_w,
                                          Wqkv, Wo, W13, W2, tpos, ROPT,
                                          x, ln1_w, H);
    // QKV GEMM + fused RoPE + fused V-transpose (256x192, 4-phase + reg pipeline)
    gemm256<0><<<dim3(16, 16), 512, 0, stream>>>(H, Wqkv, QR, KR, VT, ROPT, 3072, 1024);
    attn_k<<<dim3(16, 32), 256, 0, stream>>>(QR, KR, VT, CTX);
    // attn-out projection (128x128, 2-phase counted, 256 blocks = 1 round)
    gemm_thin<<<dim3(8, 32), 512, 0, stream>>>(CTX, Wo, X1, x, 1024, 1024);
    rmsnorm_k<<<4096, 256, 0, stream>>>(X1, ln2_w, H2);
    // W13 GEMM + fused SwiGLU (w1/w3 row-interleaved, 256x192, 4-phase + pipeline)
    gemm256<1><<<dim3(28, 16), 512, 0, stream>>>(H2, W13, ACT, nullptr, nullptr, nullptr, 5376, 1024);
    // FFN down-projection (128x128, 2-phase counted, K=2688)
    gemm_thin<<<dim3(8, 32), 512, 0, stream>>>(ACT, W2, out, X1, 1024, 2688);
}